// Round 12
// baseline (523.308 us; speedup 1.0000x reference)
//
#include <hip/hip_runtime.h>

#define NN 50000
#define NE 600000
#define NB 4096
#define DD 128
#define EPSV 1e-5f
#define NBKT 196     // ceil(50000/256) buckets of 256 node ids (per side)
#define NCHUNK 256   // edge chunks per side
#define CHSZ ((NE + NCHUNK - 1) / NCHUNK)   // 2344

typedef __bf16 bf16x8 __attribute__((ext_vector_type(8)));
typedef float f32x4 __attribute__((ext_vector_type(4)));
typedef float f32x2 __attribute__((ext_vector_type(2)));

__device__ inline unsigned short f2bf(float f) {
    unsigned u = __float_as_uint(f);
    u = (u + 0x7FFFu + ((u >> 16) & 1u)) >> 16;
    return (unsigned short)u;
}
__device__ inline float bf2f(unsigned short h) {
    return __uint_as_float(((unsigned)h) << 16);
}

// ---------------- fused prep: x cvt + weight cvt + edge histogram (independent, block-range) ----
// wf layout (per layer l): 64 fragments f = (ntile*8 + kc), each 1024 ushorts:
//   [0..511] hi: lane = kq*16+fm holds W[n=ntile*16+fm][k=kc*32+kq*8+j], j=0..7; [512..1023] lo.
__global__ void k_prep(const float* __restrict__ x1, const float* __restrict__ x2,
                       unsigned short* __restrict__ xh, unsigned short* __restrict__ xl,
                       const float* __restrict__ Wl, const float* __restrict__ Wr,
                       const float* __restrict__ W1,
                       unsigned short* __restrict__ wf, unsigned* __restrict__ w1p,
                       const int* __restrict__ d0, const int* __restrict__ d1,
                       int* __restrict__ bcnt) {
    __shared__ int h[NBKT];
    int b = blockIdx.x;
    int tid = threadIdx.x;
    if (b < 12500) {
        int i = b * 256 + tid;               // over 2*NN*32 float4 groups (exact)
        const float* x = (i < NN * 32) ? x1 : x2;
        int j = (i < NN * 32) ? i : i - NN * 32;
        float4 v = ((const float4*)x)[j];
        ushort4 hh, ll;
        hh.x = f2bf(v.x); ll.x = f2bf(v.x - bf2f(hh.x));
        hh.y = f2bf(v.y); ll.y = f2bf(v.y - bf2f(hh.y));
        hh.z = f2bf(v.z); ll.z = f2bf(v.z - bf2f(hh.z));
        hh.w = f2bf(v.w); ll.w = f2bf(v.w - bf2f(hh.w));
        ((ushort4*)xh)[i] = hh;
        ((ushort4*)xl)[i] = ll;
    } else if (b < 12500 + 576) {
        int t = (b - 12500) * 256 + tid;
        if (t < 3 * 128 * 256) {
            int k = t & 255;
            int n = (t >> 8) & 127;
            int l = t >> 15;
            float w = (k < 128) ? Wl[l * 16384 + k * 128 + n] : Wr[l * 16384 + (k - 128) * 128 + n];
            unsigned short hh = f2bf(w);
            unsigned short lo = f2bf(w - bf2f(hh));
            int ntile = n >> 4, fm = n & 15, kc = k >> 5, kq = (k & 31) >> 3, j = k & 7;
            size_t pos = (size_t)l * 65536 + (size_t)(ntile * 8 + kc) * 1024 +
                         (size_t)(kq * 16 + fm) * 8 + j;
            wf[pos] = hh;
            wf[pos + 512] = lo;
        } else if (t < 3 * 128 * 256 + 128 * 384) {
            int u = t - 3 * 128 * 256;
            int n = u / 384;
            int k = u - n * 384;
            float w = W1[k * 128 + n];
            unsigned short hh = f2bf(w);
            unsigned short ll = f2bf(w - bf2f(hh));
            w1p[u] = ((unsigned)hh << 16) | (unsigned)ll;
        }
    } else {
        int hb = b - 13076;
        int side = (hb >= NCHUNK) ? 1 : 0;
        int c = hb - side * NCHUNK;
        const int* dst = side ? d1 : d0;
        for (int i = tid; i < NBKT; i += 256) h[i] = 0;
        __syncthreads();
        int e0 = c * CHSZ, e1 = min(e0 + CHSZ, NE);
        for (int e = e0 + tid; e < e1; e += 256) atomicAdd(&h[dst[e] >> 8], 1);
        __syncthreads();
        int* bc = bcnt + ((size_t)side * NCHUNK + c) * NBKT;
        for (int i = tid; i < NBKT; i += 256) bc[i] = h[i];
    }
}

// ---------------- CSR build stages 1-4 (atomic-free two-level counting sort) ----------------
__global__ void k_s1(int* __restrict__ bcnt, int* __restrict__ btot) {
    int side = (blockIdx.x >= NBKT) ? 1 : 0;
    int b = blockIdx.x - side * NBKT;
    int tid = threadIdx.x;            // tid == chunk
    int idx = ((size_t)side * NCHUNK + tid) * NBKT + b;
    int v = bcnt[idx];
    int lane = tid & 63, wv = tid >> 6;
    int x = v;
#pragma unroll
    for (int off = 1; off < 64; off <<= 1) {
        int y = __shfl_up(x, off, 64);
        if (lane >= off) x += y;
    }
    __shared__ int ws4[4];
    if (lane == 63) ws4[wv] = x;
    __syncthreads();
    int add = 0;
#pragma unroll
    for (int w = 0; w < 4; w++)
        if (w < wv) add += ws4[w];
    int incl = x + add;
    bcnt[idx] = incl - v;
    if (tid == 255) btot[side * NBKT + b] = incl;
}

__global__ void k_s2(const int* __restrict__ btot, int* __restrict__ bbase,
                     int* __restrict__ ptrC) {
    int side = blockIdx.x;
    int tid = threadIdx.x;
    int v = (tid < NBKT) ? btot[side * NBKT + tid] : 0;
    int lane = tid & 63, wv = tid >> 6;
    int x = v;
#pragma unroll
    for (int off = 1; off < 64; off <<= 1) {
        int y = __shfl_up(x, off, 64);
        if (lane >= off) x += y;
    }
    __shared__ int ws4[4];
    if (lane == 63) ws4[wv] = x;
    __syncthreads();
    int add = 0;
#pragma unroll
    for (int w = 0; w < 4; w++)
        if (w < wv) add += ws4[w];
    int incl = x + add;
    if (tid < NBKT) bbase[side * NBKT + tid] = incl - v;
    if (tid == 0 && side == 1) ptrC[2 * NN] = 2 * NE;
}

// partition: part[side*NE + pos] = (src_global << 8) | (dst & 255)
__global__ void k_part(const int* __restrict__ s0, const int* __restrict__ d0,
                       const int* __restrict__ s1, const int* __restrict__ d1,
                       const int* __restrict__ bcnt, const int* __restrict__ bbase,
                       int* __restrict__ part) {
    int side = (blockIdx.x >= NCHUNK) ? 1 : 0;
    int c = blockIdx.x - side * NCHUNK;
    const int* src = side ? s1 : s0;
    const int* dst = side ? d1 : d0;
    int tid = threadIdx.x;
    __shared__ int off[NBKT];
    const int* bc = bcnt + ((size_t)side * NCHUNK + c) * NBKT;
    for (int i = tid; i < NBKT; i += 256) off[i] = bbase[side * NBKT + i] + bc[i];
    __syncthreads();
    int e0 = c * CHSZ, e1 = min(e0 + CHSZ, NE);
    int* P = part + (size_t)side * NE;
    int soff = side * NN;
    for (int e = e0 + tid; e < e1; e += 256) {
        int d = dst[e];
        int pos = atomicAdd(&off[d >> 8], 1);
        P[pos] = ((src[e] + soff) << 8) | (d & 255);
    }
}

// per bucket: count, scan -> ptrC/invd (combined), place src into combined CSR
__global__ void k_csr(const int* __restrict__ part, const int* __restrict__ bbase,
                      int* __restrict__ ptrC, float* __restrict__ invdC,
                      int* __restrict__ csrC) {
    int side = (blockIdx.x >= NBKT) ? 1 : 0;
    int b = blockIdx.x - side * NBKT;
    int tid = threadIdx.x;
    const int* P = part + (size_t)side * NE;
    int base = bbase[side * NBKT + b];
    int endp = (b == NBKT - 1) ? NE : bbase[side * NBKT + b + 1];
    __shared__ int cnt[256];
    cnt[tid] = 0;
    __syncthreads();
    for (int e = base + tid; e < endp; e += 256) atomicAdd(&cnt[P[e] & 255], 1);
    __syncthreads();
    int v = cnt[tid];
    int lane = tid & 63, wv = tid >> 6;
    int x = v;
#pragma unroll
    for (int off = 1; off < 64; off <<= 1) {
        int y = __shfl_up(x, off, 64);
        if (lane >= off) x += y;
    }
    __shared__ int ws4[4];
    if (lane == 63) ws4[wv] = x;
    __syncthreads();
    int add = 0;
#pragma unroll
    for (int w = 0; w < 4; w++)
        if (w < wv) add += ws4[w];
    int excl = x + add - v;
    int node = (b << 8) + tid;
    if (node < NN) {
        ptrC[side * NN + node] = side * NE + base + excl;
        invdC[side * NN + node] = 1.0f / (float)(v > 1 ? v : 1);
    }
    __syncthreads();
    cnt[tid] = excl;
    __syncthreads();
    for (int e = base + tid; e < endp; e += 256) {
        int p = P[e];
        int pos = atomicAdd(&cnt[p & 255], 1);
        csrC[(size_t)side * NE + base + pos] = p >> 8;
    }
}

// ---------------- neighbor mean-aggregation: 16 edges/iter, SOFTWARE-PIPELINED loads ---------
#define ONE2 ((f32x2){1.f, 1.f})
#define ZERO2 ((f32x2){0.f, 0.f})
#define UNP2H(u) __uint_as_float((u) << 16)
#define UNP2L(u) __uint_as_float((u) & 0xffff0000u)
#define LOADG(E0, VA, VB, VC, VD, WA, WB, WC, WD)                                  \
    {                                                                              \
        int eA_ = (E0) + q, eB_ = (E0) + 4 + q, eC_ = (E0) + 8 + q, eD_ = (E0) + 12 + q; \
        int iA_ = __shfl(idxv, eA_, 64);                                           \
        int iB_ = __shfl(idxv, eB_, 64);                                           \
        int iC_ = __shfl(idxv, eC_, 64);                                           \
        int iD_ = __shfl(idxv, eD_, 64);                                           \
        WA = (eA_ < cnt) ? ONE2 : ZERO2;                                           \
        WB = (eB_ < cnt) ? ONE2 : ZERO2;                                           \
        WC = (eC_ < cnt) ? ONE2 : ZERO2;                                           \
        WD = (eD_ < cnt) ? ONE2 : ZERO2;                                           \
        VA = *(const uint4*)(xh + (((unsigned)iA_ << 7) + (c << 3)));              \
        VB = *(const uint4*)(xh + (((unsigned)iB_ << 7) + (c << 3)));              \
        VC = *(const uint4*)(xh + (((unsigned)iC_ << 7) + (c << 3)));              \
        VD = *(const uint4*)(xh + (((unsigned)iD_ << 7) + (c << 3)));              \
    }
#define PROC1(V, W)                                                                \
    a2[0] += W * (f32x2){UNP2H(V.x), UNP2L(V.x)};                                  \
    a2[1] += W * (f32x2){UNP2H(V.y), UNP2L(V.y)};                                  \
    a2[2] += W * (f32x2){UNP2H(V.z), UNP2L(V.z)};                                  \
    a2[3] += W * (f32x2){UNP2H(V.w), UNP2L(V.w)};

__global__ void k_gather(const unsigned short* __restrict__ xh, const int* __restrict__ ptr,
                         const int* __restrict__ csr, const float* __restrict__ invd,
                         unsigned short* __restrict__ aggH) {
    int wid = threadIdx.x >> 6;
    int lane = threadIdx.x & 63;
    int q = lane >> 4;        // edge slot within group of 4
    int c = lane & 15;        // column chunk: elems [c*8, c*8+8)
    int n = blockIdx.x * 4 + wid;
    if (n >= 2 * NN) return;
    int beg = ptr[n], end = ptr[n + 1];
    float id = invd[n];
    f32x2 a2[4];
#pragma unroll
    for (int k = 0; k < 4; k++) a2[k] = ZERO2;

    for (int base = beg; base < end; base += 64) {
        int cnt = min(end - base, 64);
        int idxv = csr[base + min(lane, cnt - 1)];
        uint4 cA, cB, cC, cD, nA, nB, nC, nD;
        f32x2 xA, xB, xC, xD, yA, yB, yC, yD;
        LOADG(0, cA, cB, cC, cD, xA, xB, xC, xD);
        for (int e0 = 0; e0 < cnt; e0 += 16) {
            bool more = (e0 + 16) < cnt;            // wave-uniform
            if (more) LOADG(e0 + 16, nA, nB, nC, nD, yA, yB, yC, yD);
            PROC1(cA, xA);
            PROC1(cB, xB);
            PROC1(cC, xC);
            PROC1(cD, xD);
            if (more) {
                cA = nA; cB = nB; cC = nC; cD = nD;
                xA = yA; xB = yB; xC = yC; xD = yD;
            }
        }
    }
    float a[8];
    a[0] = a2[0][0]; a[1] = a2[0][1];
    a[2] = a2[1][0]; a[3] = a2[1][1];
    a[4] = a2[2][0]; a[5] = a2[2][1];
    a[6] = a2[3][0]; a[7] = a2[3][1];
#pragma unroll
    for (int k = 0; k < 8; k++) {
        a[k] += __shfl_xor(a[k], 16, 64);
        a[k] += __shfl_xor(a[k], 32, 64);
    }
    if (q == 0) {
        unsigned short h0 = f2bf(a[0] * id), h1 = f2bf(a[1] * id);
        unsigned short h2 = f2bf(a[2] * id), h3 = f2bf(a[3] * id);
        unsigned short h4 = f2bf(a[4] * id), h5 = f2bf(a[5] * id);
        unsigned short h6 = f2bf(a[6] * id), h7 = f2bf(a[7] * id);
        uint4 o;
        o.x = (unsigned)h0 | ((unsigned)h1 << 16);
        o.y = (unsigned)h2 | ((unsigned)h3 << 16);
        o.z = (unsigned)h4 | ((unsigned)h5 << 16);
        o.w = (unsigned)h6 | ((unsigned)h7 << 16);
        *(uint4*)(aggH + (size_t)n * DD + c * 8) = o;
    }
}

// ---------------- fused SAGE layer GEMM: 64x128 tile, W in regs, BK=64 (2 chunks/barrier) -----
// 4 phases; phases 0-1 stage A-slab k=(p&1)*64, phases 2-3 stage X-slab k=(p&1)*64 (hi+lo).
// LDS [64 rows][64 shorts] with XOR slot swizzle (slot = seg ^ (row&7)). W fragments straight
// from L2 (fragment-linear wf), never in LDS. LDS 16 KB, reused as C buffer in epilogue.
__launch_bounds__(256)
__global__ void k_gemmW(const unsigned short* __restrict__ AH,
                        const unsigned short* __restrict__ XH, const unsigned short* __restrict__ XL,
                        const unsigned short* __restrict__ wf,
                        const float* __restrict__ bl, const float* __restrict__ g,
                        const float* __restrict__ be, const float* __restrict__ mn,
                        const float* __restrict__ vr,
                        unsigned short* __restrict__ OH, unsigned short* __restrict__ OL,
                        float* __restrict__ Of, int f32out) {
    __shared__ __align__(16) unsigned short sBuf[8192];   // hi [0,4096): [64][64]; lo [4096,8192)
    int tid = threadIdx.x;
    int lane = tid & 63, w = tid >> 6;
    int fm = lane & 15, kq = lane >> 4;
    int m0 = blockIdx.x * 64;
    int wr = (w & 1) * 32;
    int wn = (w >> 1) * 64;

    // staging coords: 512 slots (2/thread): s = tid + 256*i -> row = s>>3, seg = s&7
    int soff[2];
    bool sok[2];
    size_t gb[2];
#pragma unroll
    for (int i = 0; i < 2; i++) {
        int s = tid + 256 * i;
        int row = s >> 3, seg = s & 7;
        soff[i] = row * 64 + ((seg ^ (row & 7)) << 3);
        sok[i] = (m0 + row) < 2 * NN;
        gb[i] = (size_t)(m0 + row) * DD + seg * 8;
    }

    float scv[4], shv[4];
#pragma unroll
    for (int nt = 0; nt < 4; nt++) {
        int jj = wn + nt * 16 + fm;
        float s = g[jj] * rsqrtf(vr[jj] + EPSV);
        scv[nt] = s;
        shv[nt] = (bl[jj] - mn[jj]) * s + be[jj];
    }

    f32x4 acc[2][4];
#pragma unroll
    for (int i = 0; i < 2; i++)
#pragma unroll
        for (int j = 0; j < 4; j++) acc[i][j] = (f32x4){0.f, 0.f, 0.f, 0.f};

    const unsigned short* wfb = wf + (size_t)((w >> 1) * 4) * 8192 + lane * 8;
    int r0 = wr + fm, r1 = wr + 16 + fm;
    int rx0 = (r0 & 7), rx1 = (r1 & 7);

#pragma unroll
    for (int p = 0; p < 4; p++) {
        int isA = (p < 2);
        if (p > 0) __syncthreads();          // readers of prev slab done
#pragma unroll
        for (int i = 0; i < 2; i++) {        // stage 64-k slab; k-offset within operand = (p&1)*64
            uint4 av = make_uint4(0, 0, 0, 0), lv = make_uint4(0, 0, 0, 0);
            size_t go = gb[i] + (size_t)(p & 1) * 64;
            if (sok[i]) {
                av = *(const uint4*)((isA ? AH : XH) + go);
                if (!isA) lv = *(const uint4*)(XL + go);
            }
            *(uint4*)&sBuf[soff[i]] = av;
            if (!isA) *(uint4*)&sBuf[4096 + soff[i]] = lv;
        }
        __syncthreads();                     // slab ready

#pragma unroll
        for (int cc = 0; cc < 2; cc++) {
            int ch = p * 2 + cc;
            // W fragments chunk ch -> registers (L2-resident 1KB wave loads)
            bf16x8 wh[4], wl[4];
#pragma unroll
            for (int nt = 0; nt < 4; nt++) {
                const unsigned short* pw = wfb + (size_t)(nt * 8 + ch) * 1024;
                wh[nt] = *(const bf16x8*)pw;
                wl[nt] = *(const bf16x8*)(pw + 512);
            }
            int sl = cc * 4 + kq;
            bf16x8 ah[2], al[2];
            ah[0] = *(const bf16x8*)&sBuf[r0 * 64 + ((sl ^ rx0) << 3)];
            ah[1] = *(const bf16x8*)&sBuf[r1 * 64 + ((sl ^ rx1) << 3)];
            if (!isA) {
                al[0] = *(const bf16x8*)&sBuf[4096 + r0 * 64 + ((sl ^ rx0) << 3)];
                al[1] = *(const bf16x8*)&sBuf[4096 + r1 * 64 + ((sl ^ rx1) << 3)];
            }
#pragma unroll
            for (int nt = 0; nt < 4; nt++) {
#pragma unroll
                for (int mt = 0; mt < 2; mt++) {
                    acc[mt][nt] = __builtin_amdgcn_mfma_f32_16x16x32_bf16(ah[mt], wh[nt], acc[mt][nt], 0, 0, 0);
                    acc[mt][nt] = __builtin_amdgcn_mfma_f32_16x16x32_bf16(ah[mt], wl[nt], acc[mt][nt], 0, 0, 0);
                    if (!isA)
                        acc[mt][nt] = __builtin_amdgcn_mfma_f32_16x16x32_bf16(al[mt], wh[nt], acc[mt][nt], 0, 0, 0);
                }
            }
        }
    }

    // ---- epilogue: BN+relu -> packed uint -> 32-row LDS buffer -> coalesced 16B stores ----
    unsigned* cb = (unsigned*)sBuf;          // 32 rows x 128 cols = 16 KB
    int c8 = tid & 15;
    for (int h = 0; h < 2; h++) {
        __syncthreads();
        if ((w & 1) == h) {                  // waves with wr == h*32
#pragma unroll
            for (int mt = 0; mt < 2; mt++) {
#pragma unroll
                for (int r = 0; r < 4; r++) {
                    int rh = mt * 16 + kq * 4 + r;   // 0..31
#pragma unroll
                    for (int nt = 0; nt < 4; nt++) {
                        int col = wn + nt * 16 + fm;
                        float o = fmaxf(acc[mt][nt][r] * scv[nt] + shv[nt], 0.f);
                        unsigned pv;
                        if (f32out) {
                            pv = __float_as_uint(o);
                        } else {
                            unsigned short hi_ = f2bf(o);
                            pv = ((unsigned)hi_ << 16) | (unsigned)f2bf(o - bf2f(hi_));
                        }
                        cb[rh * 128 + col] = pv;
                    }
                }
            }
        }
        __syncthreads();
        if (f32out) {
#pragma unroll
            for (int j = 0; j < 4; j++) {
                int row = (tid >> 5) + j * 8;
                int grow = m0 + h * 32 + row;
                if (grow < 2 * NN)
                    *(uint4*)&Of[(size_t)grow * DD + (tid & 31) * 4] =
                        *(const uint4*)&cb[row * 128 + (tid & 31) * 4];
            }
        } else {
#pragma unroll
            for (int j = 0; j < 2; j++) {
                int row = (tid >> 4) + j * 16;
                int grow = m0 + h * 32 + row;
                if (grow < 2 * NN) {
                    const unsigned* u = &cb[row * 128 + c8 * 8];
                    uint4 hv, lv2;
                    hv.x = (u[0] >> 16) | (u[1] & 0xFFFF0000u);
                    hv.y = (u[2] >> 16) | (u[3] & 0xFFFF0000u);
                    hv.z = (u[4] >> 16) | (u[5] & 0xFFFF0000u);
                    hv.w = (u[6] >> 16) | (u[7] & 0xFFFF0000u);
                    lv2.x = (u[0] & 0xFFFFu) | (u[1] << 16);
                    lv2.y = (u[2] & 0xFFFFu) | (u[3] << 16);
                    lv2.z = (u[4] & 0xFFFFu) | (u[5] << 16);
                    lv2.w = (u[6] & 0xFFFFu) | (u[7] << 16);
                    *(uint4*)&OH[(size_t)grow * DD + c8 * 8] = hv;
                    *(uint4*)&OL[(size_t)grow * DD + c8 * 8] = lv2;
                }
            }
        }
    }
}

// ---------------- global add pool fused with z build (atomic-free: batch sorted) ----------------
__launch_bounds__(128)
__global__ void k_pool2z(const float* __restrict__ cf, const int* __restrict__ bt1,
                         const int* __restrict__ bt2, const int* __restrict__ rel,
                         const float* __restrict__ kge,
                         unsigned short* __restrict__ zh, unsigned short* __restrict__ zl) {
    int side = (blockIdx.x >= NB) ? 1 : 0;
    int b = blockIdx.x - side * NB;
    const int* batch = side ? bt2 : bt1;
    const float* h = cf + (size_t)side * NN * DD;
    __shared__ int sr[2];
    if (threadIdx.x < 2) {
        int target = b + (int)threadIdx.x;
        int lo = 0, hi = NN;
        while (lo < hi) {
            int mid = (lo + hi) >> 1;
            if (batch[mid] < target) lo = mid + 1; else hi = mid;
        }
        sr[threadIdx.x] = lo;
    }
    __syncthreads();
    int beg = sr[0], end = sr[1];
    int t = threadIdx.x;
    float acc = 0.f;
    for (int r = beg; r < end; r++) acc += h[(size_t)r * DD + t];
    size_t zo = (size_t)b * 384 + side * 128 + t;
    unsigned short hh = f2bf(acc);
    zh[zo] = hh;
    zl[zo] = f2bf(acc - bf2f(hh));
    if (side == 0) {
        float kv = kge[(size_t)rel[b] * 128 + t];
        size_t zk = (size_t)b * 384 + 256 + t;
        unsigned short kh = f2bf(kv);
        zh[zk] = kh;
        zl[zk] = f2bf(kv - bf2f(kh));
    }
}

// ---------------- MLP head: split-bf16 MFMA GEMM + fused relu·W2 reduction ----------------
__launch_bounds__(256)
__global__ void k_mlp2(const unsigned short* __restrict__ zh, const unsigned short* __restrict__ zl,
                       const unsigned* __restrict__ w1p,
                       const float* __restrict__ b1, const float* __restrict__ W2,
                       const float* __restrict__ b2, float* __restrict__ out) {
    __shared__ __align__(16) unsigned short sZ[2][32 * 40];
    __shared__ __align__(16) unsigned short sW[2][128 * 40];
    __shared__ float hpart[32][4];
    int tid = threadIdx.x;
    int m0 = blockIdx.x * 32;
    int lane = tid & 63, w = tid >> 6;
    int fm = lane & 15, q = lane >> 4;
    int wn = w * 32;

    f32x4 acc[2][2];
#pragma unroll
    for (int i = 0; i < 2; i++)
#pragma unroll
        for (int j = 0; j < 2; j++) acc[i][j] = (f32x4){0.f, 0.f, 0.f, 0.f};

    for (int c = 0; c < 12; c++) {
        int k0 = c * 32;
        __syncthreads();
        {   // Z: 32 rows x 8 segs = 256 slots
            int row = tid >> 3, seg = tid & 7;
            size_t off = (size_t)(m0 + row) * 384 + k0 + seg * 4;
            *(ushort4*)&sZ[0][row * 40 + seg * 4] = *(const ushort4*)(zh + off);
            *(ushort4*)&sZ[1][row * 40 + seg * 4] = *(const ushort4*)(zl + off);
        }
#pragma unroll
        for (int i = 0; i < 4; i++) {   // W1: 128 rows x 8 segs = 1024 slots
            int u = tid + 256 * i;
            int row = u >> 3, seg = u & 7;
            uint4 val = *(const uint4*)(w1p + (size_t)row * 384 + k0 + seg * 4);
            ushort4 hi, lo;
            hi.x = val.x >> 16; hi.y = val.y >> 16; hi.z = val.z >> 16; hi.w = val.w >> 16;
            lo.x = val.x & 0xFFFF; lo.y = val.y & 0xFFFF; lo.z = val.z & 0xFFFF; lo.w = val.w & 0xFFFF;
            *(ushort4*)&sW[0][row * 40 + seg * 4] = hi;
            *(ushort4*)&sW[1][row * 40 + seg * 4] = lo;
        }
        __syncthreads();
        bf16x8 zfh[2], zfl[2];
#pragma unroll
        for (int mt = 0; mt < 2; mt++) {
            int r = mt * 16 + fm;
            zfh[mt] = *(const bf16x8*)&sZ[0][r * 40 + q * 8];
            zfl[mt] = *(const bf16x8*)&sZ[1][r * 40 + q * 8];
        }
#pragma unroll
        for (int nt = 0; nt < 2; nt++) {
            int nr = wn + nt * 16 + fm;
            bf16x8 wh = *(const bf16x8*)&sW[0][nr * 40 + q * 8];
            bf16x8 wl = *(const bf16x8*)&sW[1][nr * 40 + q * 8];
#pragma unroll
            for (int mt = 0; mt < 2; mt++) {
                acc[mt][nt] = __builtin_amdgcn_mfma_f32_16x16x32_bf16(zfh[mt], wh, acc[mt][nt], 0, 0, 0);
                acc[mt][nt] = __builtin_amdgcn_mfma_f32_16x16x32_bf16(zfh[mt], wl, acc[mt][nt], 0, 0, 0);
                acc[mt][nt] = __builtin_amdgcn_mfma_f32_16x16x32_bf16(zfl[mt], wh, acc[mt][nt], 0, 0, 0);
            }
        }
    }

    float b1v[2], w2v[2];
#pragma unroll
    for (int nt = 0; nt < 2; nt++) {
        int col = wn + nt * 16 + fm;
        b1v[nt] = b1[col];
        w2v[nt] = W2[col];
    }
#pragma unroll
    for (int mt = 0; mt < 2; mt++) {
#pragma unroll
        for (int r = 0; r < 4; r++) {
            float val = 0.f;
#pragma unroll
            for (int nt = 0; nt < 2; nt++)
                val += fmaxf(acc[mt][nt][r] + b1v[nt], 0.f) * w2v[nt];
#pragma unroll
            for (int m = 1; m < 16; m <<= 1) val += __shfl_xor(val, m, 64);
            if (fm == 0) hpart[mt * 16 + q * 4 + r][w] = val;
        }
    }
    __syncthreads();
    if (tid < 32)
        out[m0 + tid] = hpart[tid][0] + hpart[tid][1] + hpart[tid][2] + hpart[tid][3] + b2[0];
}

extern "C" void kernel_launch(void* const* d_in, const int* in_sizes, int n_in,
                              void* d_out, int out_size, void* d_ws, size_t ws_size,
                              hipStream_t stream) {
    const float* x1  = (const float*)d_in[0];
    const float* x2  = (const float*)d_in[1];
    const int*   ei1 = (const int*)d_in[2];
    const int*   ei2 = (const int*)d_in[3];
    const int*   bt1 = (const int*)d_in[4];
    const int*   bt2 = (const int*)d_in[5];
    const int*   rel = (const int*)d_in[6];
    const float* Wl  = (const float*)d_in[7];
    const float* bl  = (const float*)d_in[8];
    const float* Wr  = (const float*)d_in[9];
    const float* g   = (const float*)d_in[10];
    const float* be  = (const float*)d_in[11];
    const float* mn  = (const float*)d_in[12];
    const float* vr  = (const float*)d_in[13];
    const float* kge = (const float*)d_in[14];
    const float* W1  = (const float*)d_in[15];
    const float* b1v = (const float*)d_in[16];
    const float* W2  = (const float*)d_in[17];
    const float* b2v = (const float*)d_in[18];

    char* ws = (char*)d_ws;
    size_t off = 0;
    auto alloc = [&](size_t bytes) {
        void* p = ws + off;
        off += (bytes + 255) & ~(size_t)255;
        return p;
    };
    const size_t PL = (size_t)2 * NN * DD;      // elements per plane
    unsigned short* xbufH = (unsigned short*)alloc(PL * 2);
    unsigned short* xbufL = (unsigned short*)alloc(PL * 2);
    unsigned short* obufH = (unsigned short*)alloc(PL * 2);   // cf aliases obufH+obufL
    unsigned short* obufL = (unsigned short*)alloc(PL * 2);
    unsigned short* aggH  = (unsigned short*)alloc(PL * 2);
    unsigned short* wf    = (unsigned short*)alloc((size_t)3 * 65536 * 2);  // fragment-linear SAGE W
    unsigned* w1p  = (unsigned*)alloc((size_t)128 * 384 * 4);               // MLP W1 packed
    unsigned short* zh = (unsigned short*)alloc((size_t)NB * 384 * 2);
    unsigned short* zl = (unsigned short*)alloc((size_t)NB * 384 * 2);
    int*   bcnt    = (int*)alloc((size_t)2 * NCHUNK * NBKT * 4);
    int*   btot    = (int*)alloc((size_t)2 * NBKT * 4);
    int*   bbase   = (int*)alloc((size_t)2 * NBKT * 4);
    int*   part    = (int*)alloc((size_t)2 * NE * 4);
    int*   ptrC    = (int*)alloc((size_t)(2 * NN + 1) * 4);
    float* invdC   = (float*)alloc((size_t)2 * NN * 4);
    int*   csrC    = (int*)alloc((size_t)2 * NE * 4);
    if (off > ws_size) return;

    float* cf = (float*)obufH;   // 2NN*DD fp32 spans obufH+obufL (contiguous)

    const int nbPrep  = 12500 + 576 + 512;           // cvt + wcvt + hist, block-range fused
    const int nbNode4 = (2 * NN + 3) / 4;            // 25000
    const int nbGemmW = (2 * NN + 63) / 64;          // 1563

    k_prep<<<nbPrep, 256, 0, stream>>>(x1, x2, xbufH, xbufL, Wl, Wr, W1, wf, w1p,
                                       ei1 + NE, ei2 + NE, bcnt);

    // atomic-free combined CSR build (LDS atomics only)
    k_s1<<<2 * NBKT, 256, 0, stream>>>(bcnt, btot);
    k_s2<<<2, 256, 0, stream>>>(btot, bbase, ptrC);
    k_part<<<2 * NCHUNK, 256, 0, stream>>>(ei1, ei1 + NE, ei2, ei2 + NE, bcnt, bbase, part);
    k_csr<<<2 * NBKT, 256, 0, stream>>>(part, bbase, ptrC, invdC, csrC);

    // layer 0
    k_gather<<<nbNode4, 256, 0, stream>>>(xbufH, ptrC, csrC, invdC, aggH);
    k_gemmW<<<nbGemmW, 256, 0, stream>>>(aggH, xbufH, xbufL, wf, bl, g, be, mn, vr,
                                         obufH, obufL, (float*)nullptr, 0);
    // layer 1
    k_gather<<<nbNode4, 256, 0, stream>>>(obufH, ptrC, csrC, invdC, aggH);
    k_gemmW<<<nbGemmW, 256, 0, stream>>>(aggH, obufH, obufL, wf + 65536, bl + 128, g + 128,
                                         be + 128, mn + 128, vr + 128,
                                         xbufH, xbufL, (float*)nullptr, 0);
    // layer 2 -> fp32 (aliases obuf)
    k_gather<<<nbNode4, 256, 0, stream>>>(xbufH, ptrC, csrC, invdC, aggH);
    k_gemmW<<<nbGemmW, 256, 0, stream>>>(aggH, xbufH, xbufL, wf + 131072, bl + 256, g + 256,
                                         be + 256, mn + 256, vr + 256,
                                         (unsigned short*)nullptr, (unsigned short*)nullptr, cf, 1);

    k_pool2z<<<2 * NB, 128, 0, stream>>>(cf, bt1, bt2, rel, kge, zh, zl);
    k_mlp2<<<NB / 32, 256, 0, stream>>>(zh, zl, w1p, b1v, W2, b2v, (float*)d_out);
}

// Round 13
// 422.876 us; speedup vs baseline: 1.2375x; 1.2375x over previous
//
#include <hip/hip_runtime.h>

#define NN 50000
#define NE 600000
#define NB 4096
#define DD 128
#define EPSV 1e-5f
#define NBKT 196     // ceil(50000/256) buckets of 256 node ids (per side)
#define NCHUNK 256   // edge chunks per side
#define CHSZ ((NE + NCHUNK - 1) / NCHUNK)   // 2344

typedef __bf16 bf16x8 __attribute__((ext_vector_type(8)));
typedef float f32x4 __attribute__((ext_vector_type(4)));
typedef float f32x2 __attribute__((ext_vector_type(2)));

__device__ inline unsigned short f2bf(float f) {
    unsigned u = __float_as_uint(f);
    u = (u + 0x7FFFu + ((u >> 16) & 1u)) >> 16;
    return (unsigned short)u;
}
__device__ inline float bf2f(unsigned short h) {
    return __uint_as_float(((unsigned)h) << 16);
}

// ---------------- fused prep: x cvt + weight cvt + edge histogram (independent, block-range) ----
// wf layout (per layer l): 64 fragments f = (ntile*8 + kc), each 1024 ushorts:
//   [0..511] hi: lane = kq*16+fm holds W[n=ntile*16+fm][k=kc*32+kq*8+j], j=0..7; [512..1023] lo.
__global__ void k_prep(const float* __restrict__ x1, const float* __restrict__ x2,
                       unsigned short* __restrict__ xh, unsigned short* __restrict__ xl,
                       const float* __restrict__ Wl, const float* __restrict__ Wr,
                       const float* __restrict__ W1,
                       unsigned short* __restrict__ wf, unsigned* __restrict__ w1p,
                       const int* __restrict__ d0, const int* __restrict__ d1,
                       int* __restrict__ bcnt) {
    __shared__ int h[NBKT];
    int b = blockIdx.x;
    int tid = threadIdx.x;
    if (b < 12500) {
        int i = b * 256 + tid;               // over 2*NN*32 float4 groups (exact)
        const float* x = (i < NN * 32) ? x1 : x2;
        int j = (i < NN * 32) ? i : i - NN * 32;
        float4 v = ((const float4*)x)[j];
        ushort4 hh, ll;
        hh.x = f2bf(v.x); ll.x = f2bf(v.x - bf2f(hh.x));
        hh.y = f2bf(v.y); ll.y = f2bf(v.y - bf2f(hh.y));
        hh.z = f2bf(v.z); ll.z = f2bf(v.z - bf2f(hh.z));
        hh.w = f2bf(v.w); ll.w = f2bf(v.w - bf2f(hh.w));
        ((ushort4*)xh)[i] = hh;
        ((ushort4*)xl)[i] = ll;
    } else if (b < 12500 + 576) {
        int t = (b - 12500) * 256 + tid;
        if (t < 3 * 128 * 256) {
            int k = t & 255;
            int n = (t >> 8) & 127;
            int l = t >> 15;
            float w = (k < 128) ? Wl[l * 16384 + k * 128 + n] : Wr[l * 16384 + (k - 128) * 128 + n];
            unsigned short hh = f2bf(w);
            unsigned short lo = f2bf(w - bf2f(hh));
            int ntile = n >> 4, fm = n & 15, kc = k >> 5, kq = (k & 31) >> 3, j = k & 7;
            size_t pos = (size_t)l * 65536 + (size_t)(ntile * 8 + kc) * 1024 +
                         (size_t)(kq * 16 + fm) * 8 + j;
            wf[pos] = hh;
            wf[pos + 512] = lo;
        } else if (t < 3 * 128 * 256 + 128 * 384) {
            int u = t - 3 * 128 * 256;
            int n = u / 384;
            int k = u - n * 384;
            float w = W1[k * 128 + n];
            unsigned short hh = f2bf(w);
            unsigned short ll = f2bf(w - bf2f(hh));
            w1p[u] = ((unsigned)hh << 16) | (unsigned)ll;
        }
    } else {
        int hb = b - 13076;
        int side = (hb >= NCHUNK) ? 1 : 0;
        int c = hb - side * NCHUNK;
        const int* dst = side ? d1 : d0;
        for (int i = tid; i < NBKT; i += 256) h[i] = 0;
        __syncthreads();
        int e0 = c * CHSZ, e1 = min(e0 + CHSZ, NE);
        for (int e = e0 + tid; e < e1; e += 256) atomicAdd(&h[dst[e] >> 8], 1);
        __syncthreads();
        int* bc = bcnt + ((size_t)side * NCHUNK + c) * NBKT;
        for (int i = tid; i < NBKT; i += 256) bc[i] = h[i];
    }
}

// ---------------- CSR build stages 1-4 (atomic-free two-level counting sort) ----------------
__global__ void k_s1(int* __restrict__ bcnt, int* __restrict__ btot) {
    int side = (blockIdx.x >= NBKT) ? 1 : 0;
    int b = blockIdx.x - side * NBKT;
    int tid = threadIdx.x;            // tid == chunk
    int idx = ((size_t)side * NCHUNK + tid) * NBKT + b;
    int v = bcnt[idx];
    int lane = tid & 63, wv = tid >> 6;
    int x = v;
#pragma unroll
    for (int off = 1; off < 64; off <<= 1) {
        int y = __shfl_up(x, off, 64);
        if (lane >= off) x += y;
    }
    __shared__ int ws4[4];
    if (lane == 63) ws4[wv] = x;
    __syncthreads();
    int add = 0;
#pragma unroll
    for (int w = 0; w < 4; w++)
        if (w < wv) add += ws4[w];
    int incl = x + add;
    bcnt[idx] = incl - v;
    if (tid == 255) btot[side * NBKT + b] = incl;
}

__global__ void k_s2(const int* __restrict__ btot, int* __restrict__ bbase,
                     int* __restrict__ ptrC) {
    int side = blockIdx.x;
    int tid = threadIdx.x;
    int v = (tid < NBKT) ? btot[side * NBKT + tid] : 0;
    int lane = tid & 63, wv = tid >> 6;
    int x = v;
#pragma unroll
    for (int off = 1; off < 64; off <<= 1) {
        int y = __shfl_up(x, off, 64);
        if (lane >= off) x += y;
    }
    __shared__ int ws4[4];
    if (lane == 63) ws4[wv] = x;
    __syncthreads();
    int add = 0;
#pragma unroll
    for (int w = 0; w < 4; w++)
        if (w < wv) add += ws4[w];
    int incl = x + add;
    if (tid < NBKT) bbase[side * NBKT + tid] = incl - v;
    if (tid == 0 && side == 1) ptrC[2 * NN] = 2 * NE;
}

// partition: part[side*NE + pos] = (src_global << 8) | (dst & 255)
__global__ void k_part(const int* __restrict__ s0, const int* __restrict__ d0,
                       const int* __restrict__ s1, const int* __restrict__ d1,
                       const int* __restrict__ bcnt, const int* __restrict__ bbase,
                       int* __restrict__ part) {
    int side = (blockIdx.x >= NCHUNK) ? 1 : 0;
    int c = blockIdx.x - side * NCHUNK;
    const int* src = side ? s1 : s0;
    const int* dst = side ? d1 : d0;
    int tid = threadIdx.x;
    __shared__ int off[NBKT];
    const int* bc = bcnt + ((size_t)side * NCHUNK + c) * NBKT;
    for (int i = tid; i < NBKT; i += 256) off[i] = bbase[side * NBKT + i] + bc[i];
    __syncthreads();
    int e0 = c * CHSZ, e1 = min(e0 + CHSZ, NE);
    int* P = part + (size_t)side * NE;
    int soff = side * NN;
    for (int e = e0 + tid; e < e1; e += 256) {
        int d = dst[e];
        int pos = atomicAdd(&off[d >> 8], 1);
        P[pos] = ((src[e] + soff) << 8) | (d & 255);
    }
}

// per bucket: count, scan -> ptrC/invd (combined), place src into combined CSR
__global__ void k_csr(const int* __restrict__ part, const int* __restrict__ bbase,
                      int* __restrict__ ptrC, float* __restrict__ invdC,
                      int* __restrict__ csrC) {
    int side = (blockIdx.x >= NBKT) ? 1 : 0;
    int b = blockIdx.x - side * NBKT;
    int tid = threadIdx.x;
    const int* P = part + (size_t)side * NE;
    int base = bbase[side * NBKT + b];
    int endp = (b == NBKT - 1) ? NE : bbase[side * NBKT + b + 1];
    __shared__ int cnt[256];
    cnt[tid] = 0;
    __syncthreads();
    for (int e = base + tid; e < endp; e += 256) atomicAdd(&cnt[P[e] & 255], 1);
    __syncthreads();
    int v = cnt[tid];
    int lane = tid & 63, wv = tid >> 6;
    int x = v;
#pragma unroll
    for (int off = 1; off < 64; off <<= 1) {
        int y = __shfl_up(x, off, 64);
        if (lane >= off) x += y;
    }
    __shared__ int ws4[4];
    if (lane == 63) ws4[wv] = x;
    __syncthreads();
    int add = 0;
#pragma unroll
    for (int w = 0; w < 4; w++)
        if (w < wv) add += ws4[w];
    int excl = x + add - v;
    int node = (b << 8) + tid;
    if (node < NN) {
        ptrC[side * NN + node] = side * NE + base + excl;
        invdC[side * NN + node] = 1.0f / (float)(v > 1 ? v : 1);
    }
    __syncthreads();
    cnt[tid] = excl;
    __syncthreads();
    for (int e = base + tid; e < endp; e += 256) {
        int p = P[e];
        int pos = atomicAdd(&cnt[p & 255], 1);
        csrC[(size_t)side * NE + base + pos] = p >> 8;
    }
}

// ---------------- neighbor mean-aggregation: 16 edges/iter (4 uint4 loads in flight/lane) -----
__global__ void k_gather(const unsigned short* __restrict__ xh, const int* __restrict__ ptr,
                         const int* __restrict__ csr, const float* __restrict__ invd,
                         unsigned short* __restrict__ aggH) {
    int wid = threadIdx.x >> 6;
    int lane = threadIdx.x & 63;
    int q = lane >> 4;        // edge slot within group of 4
    int c = lane & 15;        // column chunk: elems [c*8, c*8+8)
    int n = blockIdx.x * 4 + wid;
    if (n >= 2 * NN) return;
    int beg = ptr[n], end = ptr[n + 1];
    float id = invd[n];
    f32x2 a2[4];
#pragma unroll
    for (int k = 0; k < 4; k++) a2[k] = (f32x2){0.f, 0.f};

    for (int base = beg; base < end; base += 64) {
        int cnt = min(end - base, 64);
        int idxv = csr[base + min(lane, cnt - 1)];
        for (int e0 = 0; e0 < cnt; e0 += 16) {
            int eA = e0 + q, eB = e0 + 4 + q, eC = e0 + 8 + q, eD = e0 + 12 + q;
            int iA = __shfl(idxv, eA, 64);
            int iB = __shfl(idxv, eB, 64);
            int iC = __shfl(idxv, eC, 64);
            int iD = __shfl(idxv, eD, 64);
            f32x2 wA2 = (eA < cnt) ? (f32x2){1.f, 1.f} : (f32x2){0.f, 0.f};
            f32x2 wB2 = (eB < cnt) ? (f32x2){1.f, 1.f} : (f32x2){0.f, 0.f};
            f32x2 wC2 = (eC < cnt) ? (f32x2){1.f, 1.f} : (f32x2){0.f, 0.f};
            f32x2 wD2 = (eD < cnt) ? (f32x2){1.f, 1.f} : (f32x2){0.f, 0.f};
            uint4 vA = *(const uint4*)(xh + (((unsigned)iA << 7) + (c << 3)));
            uint4 vB = *(const uint4*)(xh + (((unsigned)iB << 7) + (c << 3)));
            uint4 vC = *(const uint4*)(xh + (((unsigned)iC << 7) + (c << 3)));
            uint4 vD = *(const uint4*)(xh + (((unsigned)iD << 7) + (c << 3)));
            a2[0] += wA2 * (f32x2){__uint_as_float(vA.x << 16), __uint_as_float(vA.x & 0xffff0000u)};
            a2[1] += wA2 * (f32x2){__uint_as_float(vA.y << 16), __uint_as_float(vA.y & 0xffff0000u)};
            a2[2] += wA2 * (f32x2){__uint_as_float(vA.z << 16), __uint_as_float(vA.z & 0xffff0000u)};
            a2[3] += wA2 * (f32x2){__uint_as_float(vA.w << 16), __uint_as_float(vA.w & 0xffff0000u)};
            a2[0] += wB2 * (f32x2){__uint_as_float(vB.x << 16), __uint_as_float(vB.x & 0xffff0000u)};
            a2[1] += wB2 * (f32x2){__uint_as_float(vB.y << 16), __uint_as_float(vB.y & 0xffff0000u)};
            a2[2] += wB2 * (f32x2){__uint_as_float(vB.z << 16), __uint_as_float(vB.z & 0xffff0000u)};
            a2[3] += wB2 * (f32x2){__uint_as_float(vB.w << 16), __uint_as_float(vB.w & 0xffff0000u)};
            a2[0] += wC2 * (f32x2){__uint_as_float(vC.x << 16), __uint_as_float(vC.x & 0xffff0000u)};
            a2[1] += wC2 * (f32x2){__uint_as_float(vC.y << 16), __uint_as_float(vC.y & 0xffff0000u)};
            a2[2] += wC2 * (f32x2){__uint_as_float(vC.z << 16), __uint_as_float(vC.z & 0xffff0000u)};
            a2[3] += wC2 * (f32x2){__uint_as_float(vC.w << 16), __uint_as_float(vC.w & 0xffff0000u)};
            a2[0] += wD2 * (f32x2){__uint_as_float(vD.x << 16), __uint_as_float(vD.x & 0xffff0000u)};
            a2[1] += wD2 * (f32x2){__uint_as_float(vD.y << 16), __uint_as_float(vD.y & 0xffff0000u)};
            a2[2] += wD2 * (f32x2){__uint_as_float(vD.z << 16), __uint_as_float(vD.z & 0xffff0000u)};
            a2[3] += wD2 * (f32x2){__uint_as_float(vD.w << 16), __uint_as_float(vD.w & 0xffff0000u)};
        }
    }
    float a[8];
    a[0] = a2[0][0]; a[1] = a2[0][1];
    a[2] = a2[1][0]; a[3] = a2[1][1];
    a[4] = a2[2][0]; a[5] = a2[2][1];
    a[6] = a2[3][0]; a[7] = a2[3][1];
#pragma unroll
    for (int k = 0; k < 8; k++) {
        a[k] += __shfl_xor(a[k], 16, 64);
        a[k] += __shfl_xor(a[k], 32, 64);
    }
    if (q == 0) {
        unsigned short h0 = f2bf(a[0] * id), h1 = f2bf(a[1] * id);
        unsigned short h2 = f2bf(a[2] * id), h3 = f2bf(a[3] * id);
        unsigned short h4 = f2bf(a[4] * id), h5 = f2bf(a[5] * id);
        unsigned short h6 = f2bf(a[6] * id), h7 = f2bf(a[7] * id);
        uint4 o;
        o.x = (unsigned)h0 | ((unsigned)h1 << 16);
        o.y = (unsigned)h2 | ((unsigned)h3 << 16);
        o.z = (unsigned)h4 | ((unsigned)h5 << 16);
        o.w = (unsigned)h6 | ((unsigned)h7 << 16);
        *(uint4*)(aggH + (size_t)n * DD + c * 8) = o;
    }
}

// ---------------- fused SAGE layer GEMM: 64x128 tile, W IN REGISTERS, A-only LDS --------------
// W comes from the fragment-linear wf array straight into registers (1KB wave-coalesced loads,
// L2-resident, NO LDS, NO barrier involvement). Only A is LDS-staged (1 load/thread/chunk,
// swizzled conflict-free). LDS 16 KB total (A 8 KB, reused as the 32-row C buffer in the
// coalesced epilogue). Grid 1563 -> ~6 blocks/CU for phase diversity.
__launch_bounds__(256)
__global__ void k_gemmW(const unsigned short* __restrict__ AH,
                        const unsigned short* __restrict__ XH, const unsigned short* __restrict__ XL,
                        const unsigned short* __restrict__ wf,
                        const float* __restrict__ bl, const float* __restrict__ g,
                        const float* __restrict__ be, const float* __restrict__ mn,
                        const float* __restrict__ vr,
                        unsigned short* __restrict__ OH, unsigned short* __restrict__ OL,
                        float* __restrict__ Of, int f32out) {
    __shared__ __align__(16) unsigned short sBuf[8192];   // A hi [0,2048) lo [2048,4096); epi 16KB
    int tid = threadIdx.x;
    int lane = tid & 63, w = tid >> 6;
    int fm = lane & 15, kq = lane >> 4;
    int m0 = blockIdx.x * 64;
    int wr = (w & 1) * 32;
    int wn = (w >> 1) * 64;
    int ksw = kq ^ ((fm >> 1) & 3);          // swizzled k-slot for fragment reads

    // staging coords: 256 slots, one per thread
    int srow = tid >> 2, sseg = tid & 3;
    int ldsoff = srow * 32 + ((sseg ^ ((srow >> 1) & 3)) << 3);
    bool sok = (m0 + srow) < 2 * NN;
    size_t gbase = (size_t)(m0 + srow) * DD + sseg * 8;

    float scv[4], shv[4];
#pragma unroll
    for (int nt = 0; nt < 4; nt++) {
        int jj = wn + nt * 16 + fm;
        float s = g[jj] * rsqrtf(vr[jj] + EPSV);
        scv[nt] = s;
        shv[nt] = (bl[jj] - mn[jj]) * s + be[jj];
    }

    f32x4 acc[2][4];
#pragma unroll
    for (int i = 0; i < 2; i++)
#pragma unroll
        for (int j = 0; j < 4; j++) acc[i][j] = (f32x4){0.f, 0.f, 0.f, 0.f};

    const unsigned short* wfb = wf + (size_t)((w >> 1) * 4) * 8192 + lane * 8;

#pragma unroll
    for (int c = 0; c < 8; c++) {
        int isA = (c < 4);
        if (c > 0) __syncthreads();          // readers of chunk c-1 done
        {   // stage A chunk c (1-2 uint4 per thread)
            uint4 av = make_uint4(0, 0, 0, 0), lv = make_uint4(0, 0, 0, 0);
            size_t gofs = gbase + (size_t)(c & 3) * 32;
            if (sok) {
                av = *(const uint4*)((isA ? AH : XH) + gofs);
                if (!isA) lv = *(const uint4*)(XL + gofs);
            }
            *(uint4*)&sBuf[ldsoff] = av;
            if (!isA) *(uint4*)&sBuf[2048 + ldsoff] = lv;
        }
        // W fragments chunk c -> registers (L2-resident 1KB wave loads, no LDS)
        bf16x8 wh[4], wl[4];
#pragma unroll
        for (int nt = 0; nt < 4; nt++) {
            const unsigned short* p = wfb + (size_t)(nt * 8 + c) * 1024;
            wh[nt] = *(const bf16x8*)p;
            wl[nt] = *(const bf16x8*)(p + 512);
        }
        __syncthreads();                     // A ready

        bf16x8 ah[2], al[2];
#pragma unroll
        for (int mt = 0; mt < 2; mt++) {
            int r = wr + mt * 16 + fm;
            ah[mt] = *(const bf16x8*)&sBuf[r * 32 + ksw * 8];
            if (!isA) al[mt] = *(const bf16x8*)&sBuf[2048 + r * 32 + ksw * 8];
        }
#pragma unroll
        for (int nt = 0; nt < 4; nt++) {
#pragma unroll
            for (int mt = 0; mt < 2; mt++) {
                acc[mt][nt] = __builtin_amdgcn_mfma_f32_16x16x32_bf16(ah[mt], wh[nt], acc[mt][nt], 0, 0, 0);
                acc[mt][nt] = __builtin_amdgcn_mfma_f32_16x16x32_bf16(ah[mt], wl[nt], acc[mt][nt], 0, 0, 0);
                if (!isA)
                    acc[mt][nt] = __builtin_amdgcn_mfma_f32_16x16x32_bf16(al[mt], wh[nt], acc[mt][nt], 0, 0, 0);
            }
        }
    }

    // ---- epilogue: BN+relu -> packed uint -> 32-row LDS buffer -> coalesced 16B stores ----
    unsigned* cb = (unsigned*)sBuf;          // 32 rows x 128 cols = 16 KB
    int c8 = tid & 15;
    for (int h = 0; h < 2; h++) {
        __syncthreads();
        if ((w & 1) == h) {                  // waves with wr == h*32
#pragma unroll
            for (int mt = 0; mt < 2; mt++) {
#pragma unroll
                for (int r = 0; r < 4; r++) {
                    int rh = mt * 16 + kq * 4 + r;   // 0..31
#pragma unroll
                    for (int nt = 0; nt < 4; nt++) {
                        int col = wn + nt * 16 + fm;
                        float o = fmaxf(acc[mt][nt][r] * scv[nt] + shv[nt], 0.f);
                        unsigned pv;
                        if (f32out) {
                            pv = __float_as_uint(o);
                        } else {
                            unsigned short hi_ = f2bf(o);
                            pv = ((unsigned)hi_ << 16) | (unsigned)f2bf(o - bf2f(hi_));
                        }
                        cb[rh * 128 + col] = pv;
                    }
                }
            }
        }
        __syncthreads();
        if (f32out) {
#pragma unroll
            for (int j = 0; j < 4; j++) {
                int row = (tid >> 5) + j * 8;
                int grow = m0 + h * 32 + row;
                if (grow < 2 * NN)
                    *(uint4*)&Of[(size_t)grow * DD + (tid & 31) * 4] =
                        *(const uint4*)&cb[row * 128 + (tid & 31) * 4];
            }
        } else {
#pragma unroll
            for (int j = 0; j < 2; j++) {
                int row = (tid >> 4) + j * 16;
                int grow = m0 + h * 32 + row;
                if (grow < 2 * NN) {
                    const unsigned* u = &cb[row * 128 + c8 * 8];
                    uint4 hv, lv2;
                    hv.x = (u[0] >> 16) | (u[1] & 0xFFFF0000u);
                    hv.y = (u[2] >> 16) | (u[3] & 0xFFFF0000u);
                    hv.z = (u[4] >> 16) | (u[5] & 0xFFFF0000u);
                    hv.w = (u[6] >> 16) | (u[7] & 0xFFFF0000u);
                    lv2.x = (u[0] & 0xFFFFu) | (u[1] << 16);
                    lv2.y = (u[2] & 0xFFFFu) | (u[3] << 16);
                    lv2.z = (u[4] & 0xFFFFu) | (u[5] << 16);
                    lv2.w = (u[6] & 0xFFFFu) | (u[7] << 16);
                    *(uint4*)&OH[(size_t)grow * DD + c8 * 8] = hv;
                    *(uint4*)&OL[(size_t)grow * DD + c8 * 8] = lv2;
                }
            }
        }
    }
}

// ---------------- global add pool fused with z build (atomic-free: batch sorted) ----------------
__launch_bounds__(128)
__global__ void k_pool2z(const float* __restrict__ cf, const int* __restrict__ bt1,
                         const int* __restrict__ bt2, const int* __restrict__ rel,
                         const float* __restrict__ kge,
                         unsigned short* __restrict__ zh, unsigned short* __restrict__ zl) {
    int side = (blockIdx.x >= NB) ? 1 : 0;
    int b = blockIdx.x - side * NB;
    const int* batch = side ? bt2 : bt1;
    const float* h = cf + (size_t)side * NN * DD;
    __shared__ int sr[2];
    if (threadIdx.x < 2) {
        int target = b + (int)threadIdx.x;
        int lo = 0, hi = NN;
        while (lo < hi) {
            int mid = (lo + hi) >> 1;
            if (batch[mid] < target) lo = mid + 1; else hi = mid;
        }
        sr[threadIdx.x] = lo;
    }
    __syncthreads();
    int beg = sr[0], end = sr[1];
    int t = threadIdx.x;
    float acc = 0.f;
    for (int r = beg; r < end; r++) acc += h[(size_t)r * DD + t];
    size_t zo = (size_t)b * 384 + side * 128 + t;
    unsigned short hh = f2bf(acc);
    zh[zo] = hh;
    zl[zo] = f2bf(acc - bf2f(hh));
    if (side == 0) {
        float kv = kge[(size_t)rel[b] * 128 + t];
        size_t zk = (size_t)b * 384 + 256 + t;
        unsigned short kh = f2bf(kv);
        zh[zk] = kh;
        zl[zk] = f2bf(kv - bf2f(kh));
    }
}

// ---------------- MLP head: split-bf16 MFMA GEMM + fused relu·W2 reduction ----------------
__launch_bounds__(256)
__global__ void k_mlp2(const unsigned short* __restrict__ zh, const unsigned short* __restrict__ zl,
                       const unsigned* __restrict__ w1p,
                       const float* __restrict__ b1, const float* __restrict__ W2,
                       const float* __restrict__ b2, float* __restrict__ out) {
    __shared__ __align__(16) unsigned short sZ[2][32 * 40];
    __shared__ __align__(16) unsigned short sW[2][128 * 40];
    __shared__ float hpart[32][4];
    int tid = threadIdx.x;
    int m0 = blockIdx.x * 32;
    int lane = tid & 63, w = tid >> 6;
    int fm = lane & 15, q = lane >> 4;
    int wn = w * 32;

    f32x4 acc[2][2];
#pragma unroll
    for (int i = 0; i < 2; i++)
#pragma unroll
        for (int j = 0; j < 2; j++) acc[i][j] = (f32x4){0.f, 0.f, 0.f, 0.f};

    for (int c = 0; c < 12; c++) {
        int k0 = c * 32;
        __syncthreads();
        {   // Z: 32 rows x 8 segs = 256 slots
            int row = tid >> 3, seg = tid & 7;
            size_t off = (size_t)(m0 + row) * 384 + k0 + seg * 4;
            *(ushort4*)&sZ[0][row * 40 + seg * 4] = *(const ushort4*)(zh + off);
            *(ushort4*)&sZ[1][row * 40 + seg * 4] = *(const ushort4*)(zl + off);
        }
#pragma unroll
        for (int i = 0; i < 4; i++) {   // W1: 128 rows x 8 segs = 1024 slots
            int u = tid + 256 * i;
            int row = u >> 3, seg = u & 7;
            uint4 val = *(const uint4*)(w1p + (size_t)row * 384 + k0 + seg * 4);
            ushort4 hi, lo;
            hi.x = val.x >> 16; hi.y = val.y >> 16; hi.z = val.z >> 16; hi.w = val.w >> 16;
            lo.x = val.x & 0xFFFF; lo.y = val.y & 0xFFFF; lo.z = val.z & 0xFFFF; lo.w = val.w & 0xFFFF;
            *(ushort4*)&sW[0][row * 40 + seg * 4] = hi;
            *(ushort4*)&sW[1][row * 40 + seg * 4] = lo;
        }
        __syncthreads();
        bf16x8 zfh[2], zfl[2];
#pragma unroll
        for (int mt = 0; mt < 2; mt++) {
            int r = mt * 16 + fm;
            zfh[mt] = *(const bf16x8*)&sZ[0][r * 40 + q * 8];
            zfl[mt] = *(const bf16x8*)&sZ[1][r * 40 + q * 8];
        }
#pragma unroll
        for (int nt = 0; nt < 2; nt++) {
            int nr = wn + nt * 16 + fm;
            bf16x8 wh = *(const bf16x8*)&sW[0][nr * 40 + q * 8];
            bf16x8 wl = *(const bf16x8*)&sW[1][nr * 40 + q * 8];
#pragma unroll
            for (int mt = 0; mt < 2; mt++) {
                acc[mt][nt] = __builtin_amdgcn_mfma_f32_16x16x32_bf16(zfh[mt], wh, acc[mt][nt], 0, 0, 0);
                acc[mt][nt] = __builtin_amdgcn_mfma_f32_16x16x32_bf16(zfh[mt], wl, acc[mt][nt], 0, 0, 0);
                acc[mt][nt] = __builtin_amdgcn_mfma_f32_16x16x32_bf16(zfl[mt], wh, acc[mt][nt], 0, 0, 0);
            }
        }
    }

    float b1v[2], w2v[2];
#pragma unroll
    for (int nt = 0; nt < 2; nt++) {
        int col = wn + nt * 16 + fm;
        b1v[nt] = b1[col];
        w2v[nt] = W2[col];
    }
#pragma unroll
    for (int mt = 0; mt < 2; mt++) {
#pragma unroll
        for (int r = 0; r < 4; r++) {
            float val = 0.f;
#pragma unroll
            for (int nt = 0; nt < 2; nt++)
                val += fmaxf(acc[mt][nt][r] + b1v[nt], 0.f) * w2v[nt];
#pragma unroll
            for (int m = 1; m < 16; m <<= 1) val += __shfl_xor(val, m, 64);
            if (fm == 0) hpart[mt * 16 + q * 4 + r][w] = val;
        }
    }
    __syncthreads();
    if (tid < 32)
        out[m0 + tid] = hpart[tid][0] + hpart[tid][1] + hpart[tid][2] + hpart[tid][3] + b2[0];
}

extern "C" void kernel_launch(void* const* d_in, const int* in_sizes, int n_in,
                              void* d_out, int out_size, void* d_ws, size_t ws_size,
                              hipStream_t stream) {
    const float* x1  = (const float*)d_in[0];
    const float* x2  = (const float*)d_in[1];
    const int*   ei1 = (const int*)d_in[2];
    const int*   ei2 = (const int*)d_in[3];
    const int*   bt1 = (const int*)d_in[4];
    const int*   bt2 = (const int*)d_in[5];
    const int*   rel = (const int*)d_in[6];
    const float* Wl  = (const float*)d_in[7];
    const float* bl  = (const float*)d_in[8];
    const float* Wr  = (const float*)d_in[9];
    const float* g   = (const float*)d_in[10];
    const float* be  = (const float*)d_in[11];
    const float* mn  = (const float*)d_in[12];
    const float* vr  = (const float*)d_in[13];
    const float* kge = (const float*)d_in[14];
    const float* W1  = (const float*)d_in[15];
    const float* b1v = (const float*)d_in[16];
    const float* W2  = (const float*)d_in[17];
    const float* b2v = (const float*)d_in[18];

    char* ws = (char*)d_ws;
    size_t off = 0;
    auto alloc = [&](size_t bytes) {
        void* p = ws + off;
        off += (bytes + 255) & ~(size_t)255;
        return p;
    };
    const size_t PL = (size_t)2 * NN * DD;      // elements per plane
    unsigned short* xbufH = (unsigned short*)alloc(PL * 2);
    unsigned short* xbufL = (unsigned short*)alloc(PL * 2);
    unsigned short* obufH = (unsigned short*)alloc(PL * 2);   // cf aliases obufH+obufL
    unsigned short* obufL = (unsigned short*)alloc(PL * 2);
    unsigned short* aggH  = (unsigned short*)alloc(PL * 2);
    unsigned short* wf    = (unsigned short*)alloc((size_t)3 * 65536 * 2);  // fragment-linear SAGE W
    unsigned* w1p  = (unsigned*)alloc((size_t)128 * 384 * 4);               // MLP W1 packed
    unsigned short* zh = (unsigned short*)alloc((size_t)NB * 384 * 2);
    unsigned short* zl = (unsigned short*)alloc((size_t)NB * 384 * 2);
    int*   bcnt    = (int*)alloc((size_t)2 * NCHUNK * NBKT * 4);
    int*   btot    = (int*)alloc((size_t)2 * NBKT * 4);
    int*   bbase   = (int*)alloc((size_t)2 * NBKT * 4);
    int*   part    = (int*)alloc((size_t)2 * NE * 4);
    int*   ptrC    = (int*)alloc((size_t)(2 * NN + 1) * 4);
    float* invdC   = (float*)alloc((size_t)2 * NN * 4);
    int*   csrC    = (int*)alloc((size_t)2 * NE * 4);
    if (off > ws_size) return;

    float* cf = (float*)obufH;   // 2NN*DD fp32 spans obufH+obufL (contiguous)

    const int nbPrep  = 12500 + 576 + 512;           // cvt + wcvt + hist, block-range fused
    const int nbNode4 = (2 * NN + 3) / 4;            // 25000
    const int nbGemmW = (2 * NN + 63) / 64;          // 1563

    k_prep<<<nbPrep, 256, 0, stream>>>(x1, x2, xbufH, xbufL, Wl, Wr, W1, wf, w1p,
                                       ei1 + NE, ei2 + NE, bcnt);

    // atomic-free combined CSR build (LDS atomics only)
    k_s1<<<2 * NBKT, 256, 0, stream>>>(bcnt, btot);
    k_s2<<<2, 256, 0, stream>>>(btot, bbase, ptrC);
    k_part<<<2 * NCHUNK, 256, 0, stream>>>(ei1, ei1 + NE, ei2, ei2 + NE, bcnt, bbase, part);
    k_csr<<<2 * NBKT, 256, 0, stream>>>(part, bbase, ptrC, invdC, csrC);

    // layer 0
    k_gather<<<nbNode4, 256, 0, stream>>>(xbufH, ptrC, csrC, invdC, aggH);
    k_gemmW<<<nbGemmW, 256, 0, stream>>>(aggH, xbufH, xbufL, wf, bl, g, be, mn, vr,
                                         obufH, obufL, (float*)nullptr, 0);
    // layer 1
    k_gather<<<nbNode4, 256, 0, stream>>>(obufH, ptrC, csrC, invdC, aggH);
    k_gemmW<<<nbGemmW, 256, 0, stream>>>(aggH, obufH, obufL, wf + 65536, bl + 128, g + 128,
                                         be + 128, mn + 128, vr + 128,
                                         xbufH, xbufL, (float*)nullptr, 0);
    // layer 2 -> fp32 (aliases obuf)
    k_gather<<<nbNode4, 256, 0, stream>>>(xbufH, ptrC, csrC, invdC, aggH);
    k_gemmW<<<nbGemmW, 256, 0, stream>>>(aggH, xbufH, xbufL, wf + 131072, bl + 256, g + 256,
                                         be + 256, mn + 256, vr + 256,
                                         (unsigned short*)nullptr, (unsigned short*)nullptr, cf, 1);

    k_pool2z<<<2 * NB, 128, 0, stream>>>(cf, bt1, bt2, rel, kge, zh, zl);
    k_mlp2<<<NB / 32, 256, 0, stream>>>(zh, zl, w1p, b1v, W2, b2v, (float*)d_out);
}

// Round 15
// 417.973 us; speedup vs baseline: 1.2520x; 1.0117x over previous
//
#include <hip/hip_runtime.h>

#define NN 50000
#define NE 600000
#define NB 4096
#define DD 128
#define EPSV 1e-5f
#define NBKT 196     // ceil(50000/256) buckets of 256 node ids (per side)
#define NCHUNK 256   // edge chunks per side
#define CHSZ ((NE + NCHUNK - 1) / NCHUNK)   // 2344

typedef __bf16 bf16x8 __attribute__((ext_vector_type(8)));
typedef float f32x4 __attribute__((ext_vector_type(4)));
typedef float f32x2 __attribute__((ext_vector_type(2)));

__device__ inline unsigned short f2bf(float f) {
    unsigned u = __float_as_uint(f);
    u = (u + 0x7FFFu + ((u >> 16) & 1u)) >> 16;
    return (unsigned short)u;
}
__device__ inline float bf2f(unsigned short h) {
    return __uint_as_float(((unsigned)h) << 16);
}

// ---------------- fused prep: x cvt + weight cvt + edge histogram (independent, block-range) ----
// wf layout (per layer l): 64 fragments f = (ntile*8 + kc), each 1024 ushorts:
//   [0..511] hi: lane = kq*16+fm holds W[n=ntile*16+fm][k=kc*32+kq*8+j], j=0..7; [512..1023] lo.
__global__ void k_prep(const float* __restrict__ x1, const float* __restrict__ x2,
                       unsigned short* __restrict__ xh, unsigned short* __restrict__ xl,
                       const float* __restrict__ Wl, const float* __restrict__ Wr,
                       const float* __restrict__ W1,
                       unsigned short* __restrict__ wf, unsigned* __restrict__ w1p,
                       const int* __restrict__ d0, const int* __restrict__ d1,
                       int* __restrict__ bcnt) {
    __shared__ int h[NBKT];
    int b = blockIdx.x;
    int tid = threadIdx.x;
    if (b < 12500) {
        int i = b * 256 + tid;               // over 2*NN*32 float4 groups (exact)
        const float* x = (i < NN * 32) ? x1 : x2;
        int j = (i < NN * 32) ? i : i - NN * 32;
        float4 v = ((const float4*)x)[j];
        ushort4 hh, ll;
        hh.x = f2bf(v.x); ll.x = f2bf(v.x - bf2f(hh.x));
        hh.y = f2bf(v.y); ll.y = f2bf(v.y - bf2f(hh.y));
        hh.z = f2bf(v.z); ll.z = f2bf(v.z - bf2f(hh.z));
        hh.w = f2bf(v.w); ll.w = f2bf(v.w - bf2f(hh.w));
        ((ushort4*)xh)[i] = hh;
        ((ushort4*)xl)[i] = ll;
    } else if (b < 12500 + 576) {
        int t = (b - 12500) * 256 + tid;
        if (t < 3 * 128 * 256) {
            int k = t & 255;
            int n = (t >> 8) & 127;
            int l = t >> 15;
            float w = (k < 128) ? Wl[l * 16384 + k * 128 + n] : Wr[l * 16384 + (k - 128) * 128 + n];
            unsigned short hh = f2bf(w);
            unsigned short lo = f2bf(w - bf2f(hh));
            int ntile = n >> 4, fm = n & 15, kc = k >> 5, kq = (k & 31) >> 3, j = k & 7;
            size_t pos = (size_t)l * 65536 + (size_t)(ntile * 8 + kc) * 1024 +
                         (size_t)(kq * 16 + fm) * 8 + j;
            wf[pos] = hh;
            wf[pos + 512] = lo;
        } else if (t < 3 * 128 * 256 + 128 * 384) {
            int u = t - 3 * 128 * 256;
            int n = u / 384;
            int k = u - n * 384;
            float w = W1[k * 128 + n];
            unsigned short hh = f2bf(w);
            unsigned short ll = f2bf(w - bf2f(hh));
            w1p[u] = ((unsigned)hh << 16) | (unsigned)ll;
        }
    } else {
        int hb = b - 13076;
        int side = (hb >= NCHUNK) ? 1 : 0;
        int c = hb - side * NCHUNK;
        const int* dst = side ? d1 : d0;
        for (int i = tid; i < NBKT; i += 256) h[i] = 0;
        __syncthreads();
        int e0 = c * CHSZ, e1 = min(e0 + CHSZ, NE);
        for (int e = e0 + tid; e < e1; e += 256) atomicAdd(&h[dst[e] >> 8], 1);
        __syncthreads();
        int* bc = bcnt + ((size_t)side * NCHUNK + c) * NBKT;
        for (int i = tid; i < NBKT; i += 256) bc[i] = h[i];
    }
}

// ---------------- CSR build stages 1-4 (atomic-free two-level counting sort) ----------------
__global__ void k_s1(int* __restrict__ bcnt, int* __restrict__ btot) {
    int side = (blockIdx.x >= NBKT) ? 1 : 0;
    int b = blockIdx.x - side * NBKT;
    int tid = threadIdx.x;            // tid == chunk
    int idx = ((size_t)side * NCHUNK + tid) * NBKT + b;
    int v = bcnt[idx];
    int lane = tid & 63, wv = tid >> 6;
    int x = v;
#pragma unroll
    for (int off = 1; off < 64; off <<= 1) {
        int y = __shfl_up(x, off, 64);
        if (lane >= off) x += y;
    }
    __shared__ int ws4[4];
    if (lane == 63) ws4[wv] = x;
    __syncthreads();
    int add = 0;
#pragma unroll
    for (int w = 0; w < 4; w++)
        if (w < wv) add += ws4[w];
    int incl = x + add;
    bcnt[idx] = incl - v;
    if (tid == 255) btot[side * NBKT + b] = incl;
}

__global__ void k_s2(const int* __restrict__ btot, int* __restrict__ bbase,
                     int* __restrict__ ptrC) {
    int side = blockIdx.x;
    int tid = threadIdx.x;
    int v = (tid < NBKT) ? btot[side * NBKT + tid] : 0;
    int lane = tid & 63, wv = tid >> 6;
    int x = v;
#pragma unroll
    for (int off = 1; off < 64; off <<= 1) {
        int y = __shfl_up(x, off, 64);
        if (lane >= off) x += y;
    }
    __shared__ int ws4[4];
    if (lane == 63) ws4[wv] = x;
    __syncthreads();
    int add = 0;
#pragma unroll
    for (int w = 0; w < 4; w++)
        if (w < wv) add += ws4[w];
    int incl = x + add;
    if (tid < NBKT) bbase[side * NBKT + tid] = incl - v;
    if (tid == 0 && side == 1) ptrC[2 * NN] = 2 * NE;
}

// partition: part[side*NE + pos] = (src_global << 8) | (dst & 255)
__global__ void k_part(const int* __restrict__ s0, const int* __restrict__ d0,
                       const int* __restrict__ s1, const int* __restrict__ d1,
                       const int* __restrict__ bcnt, const int* __restrict__ bbase,
                       int* __restrict__ part) {
    int side = (blockIdx.x >= NCHUNK) ? 1 : 0;
    int c = blockIdx.x - side * NCHUNK;
    const int* src = side ? s1 : s0;
    const int* dst = side ? d1 : d0;
    int tid = threadIdx.x;
    __shared__ int off[NBKT];
    const int* bc = bcnt + ((size_t)side * NCHUNK + c) * NBKT;
    for (int i = tid; i < NBKT; i += 256) off[i] = bbase[side * NBKT + i] + bc[i];
    __syncthreads();
    int e0 = c * CHSZ, e1 = min(e0 + CHSZ, NE);
    int* P = part + (size_t)side * NE;
    int soff = side * NN;
    for (int e = e0 + tid; e < e1; e += 256) {
        int d = dst[e];
        int pos = atomicAdd(&off[d >> 8], 1);
        P[pos] = ((src[e] + soff) << 8) | (d & 255);
    }
}

// per bucket: count, scan -> ptrC/invd (combined), place src into combined CSR
__global__ void k_csr(const int* __restrict__ part, const int* __restrict__ bbase,
                      int* __restrict__ ptrC, float* __restrict__ invdC,
                      int* __restrict__ csrC) {
    int side = (blockIdx.x >= NBKT) ? 1 : 0;
    int b = blockIdx.x - side * NBKT;
    int tid = threadIdx.x;
    const int* P = part + (size_t)side * NE;
    int base = bbase[side * NBKT + b];
    int endp = (b == NBKT - 1) ? NE : bbase[side * NBKT + b + 1];
    __shared__ int cnt[256];
    cnt[tid] = 0;
    __syncthreads();
    for (int e = base + tid; e < endp; e += 256) atomicAdd(&cnt[P[e] & 255], 1);
    __syncthreads();
    int v = cnt[tid];
    int lane = tid & 63, wv = tid >> 6;
    int x = v;
#pragma unroll
    for (int off = 1; off < 64; off <<= 1) {
        int y = __shfl_up(x, off, 64);
        if (lane >= off) x += y;
    }
    __shared__ int ws4[4];
    if (lane == 63) ws4[wv] = x;
    __syncthreads();
    int add = 0;
#pragma unroll
    for (int w = 0; w < 4; w++)
        if (w < wv) add += ws4[w];
    int excl = x + add - v;
    int node = (b << 8) + tid;
    if (node < NN) {
        ptrC[side * NN + node] = side * NE + base + excl;
        invdC[side * NN + node] = 1.0f / (float)(v > 1 ? v : 1);
    }
    __syncthreads();
    cnt[tid] = excl;
    __syncthreads();
    for (int e = base + tid; e < endp; e += 256) {
        int p = P[e];
        int pos = atomicAdd(&cnt[p & 255], 1);
        csrC[(size_t)side * NE + base + pos] = p >> 8;
    }
}

// ---------------- neighbor mean-aggregation: 16 edges/iter (4 uint4 loads in flight/lane) -----
__global__ void k_gather(const unsigned short* __restrict__ xh, const int* __restrict__ ptr,
                         const int* __restrict__ csr, const float* __restrict__ invd,
                         unsigned short* __restrict__ aggH) {
    int wid = threadIdx.x >> 6;
    int lane = threadIdx.x & 63;
    int q = lane >> 4;        // edge slot within group of 4
    int c = lane & 15;        // column chunk: elems [c*8, c*8+8)
    int n = blockIdx.x * 4 + wid;
    if (n >= 2 * NN) return;
    int beg = ptr[n], end = ptr[n + 1];
    float id = invd[n];
    f32x2 a2[4];
#pragma unroll
    for (int k = 0; k < 4; k++) a2[k] = (f32x2){0.f, 0.f};

    for (int base = beg; base < end; base += 64) {
        int cnt = min(end - base, 64);
        int idxv = csr[base + min(lane, cnt - 1)];
        for (int e0 = 0; e0 < cnt; e0 += 16) {
            int eA = e0 + q, eB = e0 + 4 + q, eC = e0 + 8 + q, eD = e0 + 12 + q;
            int iA = __shfl(idxv, eA, 64);
            int iB = __shfl(idxv, eB, 64);
            int iC = __shfl(idxv, eC, 64);
            int iD = __shfl(idxv, eD, 64);
            f32x2 wA2 = (eA < cnt) ? (f32x2){1.f, 1.f} : (f32x2){0.f, 0.f};
            f32x2 wB2 = (eB < cnt) ? (f32x2){1.f, 1.f} : (f32x2){0.f, 0.f};
            f32x2 wC2 = (eC < cnt) ? (f32x2){1.f, 1.f} : (f32x2){0.f, 0.f};
            f32x2 wD2 = (eD < cnt) ? (f32x2){1.f, 1.f} : (f32x2){0.f, 0.f};
            uint4 vA = *(const uint4*)(xh + (((unsigned)iA << 7) + (c << 3)));
            uint4 vB = *(const uint4*)(xh + (((unsigned)iB << 7) + (c << 3)));
            uint4 vC = *(const uint4*)(xh + (((unsigned)iC << 7) + (c << 3)));
            uint4 vD = *(const uint4*)(xh + (((unsigned)iD << 7) + (c << 3)));
            a2[0] += wA2 * (f32x2){__uint_as_float(vA.x << 16), __uint_as_float(vA.x & 0xffff0000u)};
            a2[1] += wA2 * (f32x2){__uint_as_float(vA.y << 16), __uint_as_float(vA.y & 0xffff0000u)};
            a2[2] += wA2 * (f32x2){__uint_as_float(vA.z << 16), __uint_as_float(vA.z & 0xffff0000u)};
            a2[3] += wA2 * (f32x2){__uint_as_float(vA.w << 16), __uint_as_float(vA.w & 0xffff0000u)};
            a2[0] += wB2 * (f32x2){__uint_as_float(vB.x << 16), __uint_as_float(vB.x & 0xffff0000u)};
            a2[1] += wB2 * (f32x2){__uint_as_float(vB.y << 16), __uint_as_float(vB.y & 0xffff0000u)};
            a2[2] += wB2 * (f32x2){__uint_as_float(vB.z << 16), __uint_as_float(vB.z & 0xffff0000u)};
            a2[3] += wB2 * (f32x2){__uint_as_float(vB.w << 16), __uint_as_float(vB.w & 0xffff0000u)};
            a2[0] += wC2 * (f32x2){__uint_as_float(vC.x << 16), __uint_as_float(vC.x & 0xffff0000u)};
            a2[1] += wC2 * (f32x2){__uint_as_float(vC.y << 16), __uint_as_float(vC.y & 0xffff0000u)};
            a2[2] += wC2 * (f32x2){__uint_as_float(vC.z << 16), __uint_as_float(vC.z & 0xffff0000u)};
            a2[3] += wC2 * (f32x2){__uint_as_float(vC.w << 16), __uint_as_float(vC.w & 0xffff0000u)};
            a2[0] += wD2 * (f32x2){__uint_as_float(vD.x << 16), __uint_as_float(vD.x & 0xffff0000u)};
            a2[1] += wD2 * (f32x2){__uint_as_float(vD.y << 16), __uint_as_float(vD.y & 0xffff0000u)};
            a2[2] += wD2 * (f32x2){__uint_as_float(vD.z << 16), __uint_as_float(vD.z & 0xffff0000u)};
            a2[3] += wD2 * (f32x2){__uint_as_float(vD.w << 16), __uint_as_float(vD.w & 0xffff0000u)};
        }
    }
    float a[8];
    a[0] = a2[0][0]; a[1] = a2[0][1];
    a[2] = a2[1][0]; a[3] = a2[1][1];
    a[4] = a2[2][0]; a[5] = a2[2][1];
    a[6] = a2[3][0]; a[7] = a2[3][1];
#pragma unroll
    for (int k = 0; k < 8; k++) {
        a[k] += __shfl_xor(a[k], 16, 64);
        a[k] += __shfl_xor(a[k], 32, 64);
    }
    if (q == 0) {
        unsigned short h0 = f2bf(a[0] * id), h1 = f2bf(a[1] * id);
        unsigned short h2 = f2bf(a[2] * id), h3 = f2bf(a[3] * id);
        unsigned short h4 = f2bf(a[4] * id), h5 = f2bf(a[5] * id);
        unsigned short h6 = f2bf(a[6] * id), h7 = f2bf(a[7] * id);
        uint4 o;
        o.x = (unsigned)h0 | ((unsigned)h1 << 16);
        o.y = (unsigned)h2 | ((unsigned)h3 << 16);
        o.z = (unsigned)h4 | ((unsigned)h5 << 16);
        o.w = (unsigned)h6 | ((unsigned)h7 << 16);
        *(uint4*)(aggH + (size_t)n * DD + c * 8) = o;
    }
}

// ---------------- fused SAGE layer GEMM: 64x128 tile, W IN REGISTERS, A-only LDS --------------
// W comes from the fragment-linear wf array straight into registers (1KB wave-coalesced loads,
// L2-resident, NO LDS, NO barrier involvement). Only A is LDS-staged (1 load/thread/chunk,
// swizzled conflict-free). LDS 16 KB total (A 8 KB, reused as the 32-row C buffer in the
// coalesced epilogue). Grid 1563 -> ~6 blocks/CU for phase diversity.
__launch_bounds__(256)
__global__ void k_gemmW(const unsigned short* __restrict__ AH,
                        const unsigned short* __restrict__ XH, const unsigned short* __restrict__ XL,
                        const unsigned short* __restrict__ wf,
                        const float* __restrict__ bl, const float* __restrict__ g,
                        const float* __restrict__ be, const float* __restrict__ mn,
                        const float* __restrict__ vr,
                        unsigned short* __restrict__ OH, unsigned short* __restrict__ OL,
                        float* __restrict__ Of, int f32out) {
    __shared__ __align__(16) unsigned short sBuf[8192];   // A hi [0,2048) lo [2048,4096); epi 16KB
    int tid = threadIdx.x;
    int lane = tid & 63, w = tid >> 6;
    int fm = lane & 15, kq = lane >> 4;
    int m0 = blockIdx.x * 64;
    int wr = (w & 1) * 32;
    int wn = (w >> 1) * 64;
    int ksw = kq ^ ((fm >> 1) & 3);          // swizzled k-slot for fragment reads

    // staging coords: 256 slots, one per thread
    int srow = tid >> 2, sseg = tid & 3;
    int ldsoff = srow * 32 + ((sseg ^ ((srow >> 1) & 3)) << 3);
    bool sok = (m0 + srow) < 2 * NN;
    size_t gbase = (size_t)(m0 + srow) * DD + sseg * 8;

    float scv[4], shv[4];
#pragma unroll
    for (int nt = 0; nt < 4; nt++) {
        int jj = wn + nt * 16 + fm;
        float s = g[jj] * rsqrtf(vr[jj] + EPSV);
        scv[nt] = s;
        shv[nt] = (bl[jj] - mn[jj]) * s + be[jj];
    }

    f32x4 acc[2][4];
#pragma unroll
    for (int i = 0; i < 2; i++)
#pragma unroll
        for (int j = 0; j < 4; j++) acc[i][j] = (f32x4){0.f, 0.f, 0.f, 0.f};

    const unsigned short* wfb = wf + (size_t)((w >> 1) * 4) * 8192 + lane * 8;

#pragma unroll
    for (int c = 0; c < 8; c++) {
        int isA = (c < 4);
        if (c > 0) __syncthreads();          // readers of chunk c-1 done
        {   // stage A chunk c (1-2 uint4 per thread)
            uint4 av = make_uint4(0, 0, 0, 0), lv = make_uint4(0, 0, 0, 0);
            size_t gofs = gbase + (size_t)(c & 3) * 32;
            if (sok) {
                av = *(const uint4*)((isA ? AH : XH) + gofs);
                if (!isA) lv = *(const uint4*)(XL + gofs);
            }
            *(uint4*)&sBuf[ldsoff] = av;
            if (!isA) *(uint4*)&sBuf[2048 + ldsoff] = lv;
        }
        // W fragments chunk c -> registers (L2-resident 1KB wave loads, no LDS)
        bf16x8 wh[4], wl[4];
#pragma unroll
        for (int nt = 0; nt < 4; nt++) {
            const unsigned short* p = wfb + (size_t)(nt * 8 + c) * 1024;
            wh[nt] = *(const bf16x8*)p;
            wl[nt] = *(const bf16x8*)(p + 512);
        }
        __syncthreads();                     // A ready

        bf16x8 ah[2], al[2];
#pragma unroll
        for (int mt = 0; mt < 2; mt++) {
            int r = wr + mt * 16 + fm;
            ah[mt] = *(const bf16x8*)&sBuf[r * 32 + ksw * 8];
            if (!isA) al[mt] = *(const bf16x8*)&sBuf[2048 + r * 32 + ksw * 8];
        }
#pragma unroll
        for (int nt = 0; nt < 4; nt++) {
#pragma unroll
            for (int mt = 0; mt < 2; mt++) {
                acc[mt][nt] = __builtin_amdgcn_mfma_f32_16x16x32_bf16(ah[mt], wh[nt], acc[mt][nt], 0, 0, 0);
                acc[mt][nt] = __builtin_amdgcn_mfma_f32_16x16x32_bf16(ah[mt], wl[nt], acc[mt][nt], 0, 0, 0);
                if (!isA)
                    acc[mt][nt] = __builtin_amdgcn_mfma_f32_16x16x32_bf16(al[mt], wh[nt], acc[mt][nt], 0, 0, 0);
            }
        }
    }

    // ---- epilogue: BN+relu -> packed uint -> 32-row LDS buffer -> coalesced 16B stores ----
    unsigned* cb = (unsigned*)sBuf;          // 32 rows x 128 cols = 16 KB
    int c8 = tid & 15;
    for (int h = 0; h < 2; h++) {
        __syncthreads();
        if ((w & 1) == h) {                  // waves with wr == h*32
#pragma unroll
            for (int mt = 0; mt < 2; mt++) {
#pragma unroll
                for (int r = 0; r < 4; r++) {
                    int rh = mt * 16 + kq * 4 + r;   // 0..31
#pragma unroll
                    for (int nt = 0; nt < 4; nt++) {
                        int col = wn + nt * 16 + fm;
                        float o = fmaxf(acc[mt][nt][r] * scv[nt] + shv[nt], 0.f);
                        unsigned pv;
                        if (f32out) {
                            pv = __float_as_uint(o);
                        } else {
                            unsigned short hi_ = f2bf(o);
                            pv = ((unsigned)hi_ << 16) | (unsigned)f2bf(o - bf2f(hi_));
                        }
                        cb[rh * 128 + col] = pv;
                    }
                }
            }
        }
        __syncthreads();
        if (f32out) {
#pragma unroll
            for (int j = 0; j < 4; j++) {
                int row = (tid >> 5) + j * 8;
                int grow = m0 + h * 32 + row;
                if (grow < 2 * NN)
                    *(uint4*)&Of[(size_t)grow * DD + (tid & 31) * 4] =
                        *(const uint4*)&cb[row * 128 + (tid & 31) * 4];
            }
        } else {
#pragma unroll
            for (int j = 0; j < 2; j++) {
                int row = (tid >> 4) + j * 16;
                int grow = m0 + h * 32 + row;
                if (grow < 2 * NN) {
                    const unsigned* u = &cb[row * 128 + c8 * 8];
                    uint4 hv, lv2;
                    hv.x = (u[0] >> 16) | (u[1] & 0xFFFF0000u);
                    hv.y = (u[2] >> 16) | (u[3] & 0xFFFF0000u);
                    hv.z = (u[4] >> 16) | (u[5] & 0xFFFF0000u);
                    hv.w = (u[6] >> 16) | (u[7] & 0xFFFF0000u);
                    lv2.x = (u[0] & 0xFFFFu) | (u[1] << 16);
                    lv2.y = (u[2] & 0xFFFFu) | (u[3] << 16);
                    lv2.z = (u[4] & 0xFFFFu) | (u[5] << 16);
                    lv2.w = (u[6] & 0xFFFFu) | (u[7] << 16);
                    *(uint4*)&OH[(size_t)grow * DD + c8 * 8] = hv;
                    *(uint4*)&OL[(size_t)grow * DD + c8 * 8] = lv2;
                }
            }
        }
    }
}

// ---------------- global add pool fused with z build (atomic-free: batch sorted) ----------------
__launch_bounds__(128)
__global__ void k_pool2z(const float* __restrict__ cf, const int* __restrict__ bt1,
                         const int* __restrict__ bt2, const int* __restrict__ rel,
                         const float* __restrict__ kge,
                         unsigned short* __restrict__ zh, unsigned short* __restrict__ zl) {
    int side = (blockIdx.x >= NB) ? 1 : 0;
    int b = blockIdx.x - side * NB;
    const int* batch = side ? bt2 : bt1;
    const float* h = cf + (size_t)side * NN * DD;
    __shared__ int sr[2];
    if (threadIdx.x < 2) {
        int target = b + (int)threadIdx.x;
        int lo = 0, hi = NN;
        while (lo < hi) {
            int mid = (lo + hi) >> 1;
            if (batch[mid] < target) lo = mid + 1; else hi = mid;
        }
        sr[threadIdx.x] = lo;
    }
    __syncthreads();
    int beg = sr[0], end = sr[1];
    int t = threadIdx.x;
    float acc = 0.f;
    for (int r = beg; r < end; r++) acc += h[(size_t)r * DD + t];
    size_t zo = (size_t)b * 384 + side * 128 + t;
    unsigned short hh = f2bf(acc);
    zh[zo] = hh;
    zl[zo] = f2bf(acc - bf2f(hh));
    if (side == 0) {
        float kv = kge[(size_t)rel[b] * 128 + t];
        size_t zk = (size_t)b * 384 + 256 + t;
        unsigned short kh = f2bf(kv);
        zh[zk] = kh;
        zl[zk] = f2bf(kv - bf2f(kh));
    }
}

// ---------------- MLP head: split-bf16 MFMA GEMM + fused relu·W2 reduction ----------------
__launch_bounds__(256)
__global__ void k_mlp2(const unsigned short* __restrict__ zh, const unsigned short* __restrict__ zl,
                       const unsigned* __restrict__ w1p,
                       const float* __restrict__ b1, const float* __restrict__ W2,
                       const float* __restrict__ b2, float* __restrict__ out) {
    __shared__ __align__(16) unsigned short sZ[2][32 * 40];
    __shared__ __align__(16) unsigned short sW[2][128 * 40];
    __shared__ float hpart[32][4];
    int tid = threadIdx.x;
    int m0 = blockIdx.x * 32;
    int lane = tid & 63, w = tid >> 6;
    int fm = lane & 15, q = lane >> 4;
    int wn = w * 32;

    f32x4 acc[2][2];
#pragma unroll
    for (int i = 0; i < 2; i++)
#pragma unroll
        for (int j = 0; j < 2; j++) acc[i][j] = (f32x4){0.f, 0.f, 0.f, 0.f};

    for (int c = 0; c < 12; c++) {
        int k0 = c * 32;
        __syncthreads();
        {   // Z: 32 rows x 8 segs = 256 slots
            int row = tid >> 3, seg = tid & 7;
            size_t off = (size_t)(m0 + row) * 384 + k0 + seg * 4;
            *(ushort4*)&sZ[0][row * 40 + seg * 4] = *(const ushort4*)(zh + off);
            *(ushort4*)&sZ[1][row * 40 + seg * 4] = *(const ushort4*)(zl + off);
        }
#pragma unroll
        for (int i = 0; i < 4; i++) {   // W1: 128 rows x 8 segs = 1024 slots
            int u = tid + 256 * i;
            int row = u >> 3, seg = u & 7;
            uint4 val = *(const uint4*)(w1p + (size_t)row * 384 + k0 + seg * 4);
            ushort4 hi, lo;
            hi.x = val.x >> 16; hi.y = val.y >> 16; hi.z = val.z >> 16; hi.w = val.w >> 16;
            lo.x = val.x & 0xFFFF; lo.y = val.y & 0xFFFF; lo.z = val.z & 0xFFFF; lo.w = val.w & 0xFFFF;
            *(ushort4*)&sW[0][row * 40 + seg * 4] = hi;
            *(ushort4*)&sW[1][row * 40 + seg * 4] = lo;
        }
        __syncthreads();
        bf16x8 zfh[2], zfl[2];
#pragma unroll
        for (int mt = 0; mt < 2; mt++) {
            int r = mt * 16 + fm;
            zfh[mt] = *(const bf16x8*)&sZ[0][r * 40 + q * 8];
            zfl[mt] = *(const bf16x8*)&sZ[1][r * 40 + q * 8];
        }
#pragma unroll
        for (int nt = 0; nt < 2; nt++) {
            int nr = wn + nt * 16 + fm;
            bf16x8 wh = *(const bf16x8*)&sW[0][nr * 40 + q * 8];
            bf16x8 wl = *(const bf16x8*)&sW[1][nr * 40 + q * 8];
#pragma unroll
            for (int mt = 0; mt < 2; mt++) {
                acc[mt][nt] = __builtin_amdgcn_mfma_f32_16x16x32_bf16(zfh[mt], wh, acc[mt][nt], 0, 0, 0);
                acc[mt][nt] = __builtin_amdgcn_mfma_f32_16x16x32_bf16(zfh[mt], wl, acc[mt][nt], 0, 0, 0);
                acc[mt][nt] = __builtin_amdgcn_mfma_f32_16x16x32_bf16(zfl[mt], wh, acc[mt][nt], 0, 0, 0);
            }
        }
    }

    float b1v[2], w2v[2];
#pragma unroll
    for (int nt = 0; nt < 2; nt++) {
        int col = wn + nt * 16 + fm;
        b1v[nt] = b1[col];
        w2v[nt] = W2[col];
    }
#pragma unroll
    for (int mt = 0; mt < 2; mt++) {
#pragma unroll
        for (int r = 0; r < 4; r++) {
            float val = 0.f;
#pragma unroll
            for (int nt = 0; nt < 2; nt++)
                val += fmaxf(acc[mt][nt][r] + b1v[nt], 0.f) * w2v[nt];
#pragma unroll
            for (int m = 1; m < 16; m <<= 1) val += __shfl_xor(val, m, 64);
            if (fm == 0) hpart[mt * 16 + q * 4 + r][w] = val;
        }
    }
    __syncthreads();
    if (tid < 32)
        out[m0 + tid] = hpart[tid][0] + hpart[tid][1] + hpart[tid][2] + hpart[tid][3] + b2[0];
}

extern "C" void kernel_launch(void* const* d_in, const int* in_sizes, int n_in,
                              void* d_out, int out_size, void* d_ws, size_t ws_size,
                              hipStream_t stream) {
    const float* x1  = (const float*)d_in[0];
    const float* x2  = (const float*)d_in[1];
    const int*   ei1 = (const int*)d_in[2];
    const int*   ei2 = (const int*)d_in[3];
    const int*   bt1 = (const int*)d_in[4];
    const int*   bt2 = (const int*)d_in[5];
    const int*   rel = (const int*)d_in[6];
    const float* Wl  = (const float*)d_in[7];
    const float* bl  = (const float*)d_in[8];
    const float* Wr  = (const float*)d_in[9];
    const float* g   = (const float*)d_in[10];
    const float* be  = (const float*)d_in[11];
    const float* mn  = (const float*)d_in[12];
    const float* vr  = (const float*)d_in[13];
    const float* kge = (const float*)d_in[14];
    const float* W1  = (const float*)d_in[15];
    const float* b1v = (const float*)d_in[16];
    const float* W2  = (const float*)d_in[17];
    const float* b2v = (const float*)d_in[18];

    char* ws = (char*)d_ws;
    size_t off = 0;
    auto alloc = [&](size_t bytes) {
        void* p = ws + off;
        off += (bytes + 255) & ~(size_t)255;
        return p;
    };
    const size_t PL = (size_t)2 * NN * DD;      // elements per plane
    unsigned short* xbufH = (unsigned short*)alloc(PL * 2);
    unsigned short* xbufL = (unsigned short*)alloc(PL * 2);
    unsigned short* obufH = (unsigned short*)alloc(PL * 2);   // cf aliases obufH+obufL
    unsigned short* obufL = (unsigned short*)alloc(PL * 2);
    unsigned short* aggH  = (unsigned short*)alloc(PL * 2);
    unsigned short* wf    = (unsigned short*)alloc((size_t)3 * 65536 * 2);  // fragment-linear SAGE W
    unsigned* w1p  = (unsigned*)alloc((size_t)128 * 384 * 4);               // MLP W1 packed
    unsigned short* zh = (unsigned short*)alloc((size_t)NB * 384 * 2);
    unsigned short* zl = (unsigned short*)alloc((size_t)NB * 384 * 2);
    int*   bcnt    = (int*)alloc((size_t)2 * NCHUNK * NBKT * 4);
    int*   btot    = (int*)alloc((size_t)2 * NBKT * 4);
    int*   bbase   = (int*)alloc((size_t)2 * NBKT * 4);
    int*   part    = (int*)alloc((size_t)2 * NE * 4);
    int*   ptrC    = (int*)alloc((size_t)(2 * NN + 1) * 4);
    float* invdC   = (float*)alloc((size_t)2 * NN * 4);
    int*   csrC    = (int*)alloc((size_t)2 * NE * 4);
    if (off > ws_size) return;

    float* cf = (float*)obufH;   // 2NN*DD fp32 spans obufH+obufL (contiguous)

    const int nbPrep  = 12500 + 576 + 512;           // cvt + wcvt + hist, block-range fused
    const int nbNode4 = (2 * NN + 3) / 4;            // 25000
    const int nbGemmW = (2 * NN + 63) / 64;          // 1563

    k_prep<<<nbPrep, 256, 0, stream>>>(x1, x2, xbufH, xbufL, Wl, Wr, W1, wf, w1p,
                                       ei1 + NE, ei2 + NE, bcnt);

    // atomic-free combined CSR build (LDS atomics only)
    k_s1<<<2 * NBKT, 256, 0, stream>>>(bcnt, btot);
    k_s2<<<2, 256, 0, stream>>>(btot, bbase, ptrC);
    k_part<<<2 * NCHUNK, 256, 0, stream>>>(ei1, ei1 + NE, ei2, ei2 + NE, bcnt, bbase, part);
    k_csr<<<2 * NBKT, 256, 0, stream>>>(part, bbase, ptrC, invdC, csrC);

    // layer 0
    k_gather<<<nbNode4, 256, 0, stream>>>(xbufH, ptrC, csrC, invdC, aggH);
    k_gemmW<<<nbGemmW, 256, 0, stream>>>(aggH, xbufH, xbufL, wf, bl, g, be, mn, vr,
                                         obufH, obufL, (float*)nullptr, 0);
    // layer 1
    k_gather<<<nbNode4, 256, 0, stream>>>(obufH, ptrC, csrC, invdC, aggH);
    k_gemmW<<<nbGemmW, 256, 0, stream>>>(aggH, obufH, obufL, wf + 65536, bl + 128, g + 128,
                                         be + 128, mn + 128, vr + 128,
                                         xbufH, xbufL, (float*)nullptr, 0);
    // layer 2 -> fp32 (aliases obuf)
    k_gather<<<nbNode4, 256, 0, stream>>>(xbufH, ptrC, csrC, invdC, aggH);
    k_gemmW<<<nbGemmW, 256, 0, stream>>>(aggH, xbufH, xbufL, wf + 131072, bl + 256, g + 256,
                                         be + 256, mn + 256, vr + 256,
                                         (unsigned short*)nullptr, (unsigned short*)nullptr, cf, 1);

    k_pool2z<<<2 * NB, 128, 0, stream>>>(cf, bt1, bt2, rel, kge, zh, zl);
    k_mlp2<<<NB / 32, 256, 0, stream>>>(zh, zl, w1p, b1v, W2, b2v, (float*)d_out);
}